// Round 1
// 355.165 us; speedup vs baseline: 1.0539x; 1.0539x over previous
//
#include <hip/hip_runtime.h>

// Problem constants: B=2, S=2048, D=1024, H=16, DH=64
constexpr int BB = 2, SS = 2048, DD = 1024, HH = 16, DHH = 64;

typedef __attribute__((ext_vector_type(4))) float f32x4;
typedef __attribute__((ext_vector_type(8))) __bf16 bf16x8;      // 4 VGPRs, MFMA A/B operand
typedef __attribute__((ext_vector_type(8))) unsigned short us8; // 16B staging vector

__device__ __forceinline__ unsigned short f32_to_bf16(float f) {
    unsigned int u = __float_as_uint(f);
    u += 0x7fffu + ((u >> 16) & 1u);   // round-to-nearest-even
    return (unsigned short)(u >> 16);
}

// packed f32x2 -> bf16x2 (RNE); gfx950 has v_cvt_pk_bf16_f32
__device__ __forceinline__ ushort2 pk_bf16(float a, float b) {
#if __has_builtin(__builtin_amdgcn_cvt_pk_bf16_f32)
    typedef __attribute__((ext_vector_type(2))) __bf16 bf16x2;
    bf16x2 r = __builtin_amdgcn_cvt_pk_bf16_f32(a, b);
    return *(ushort2*)&r;
#else
    ushort2 r; r.x = f32_to_bf16(a); r.y = f32_to_bf16(b); return r;
#endif
}
__device__ __forceinline__ ushort4 pk_bf16x4(float a, float b, float c, float d) {
    const ushort2 lo = pk_bf16(a, b), hi = pk_bf16(c, d);
    ushort4 r; r.x = lo.x; r.y = lo.y; r.z = hi.x; r.w = hi.y;
    return r;
}

__device__ __forceinline__ f32x4 mfma_bf16(bf16x8 a, bf16x8 b, f32x4 c) {
    return __builtin_amdgcn_mfma_f32_16x16x32_bf16(a, b, c, 0, 0, 0);
}

// async global->LDS DMA, 16B per lane. LDS dest = wave-uniform base + lane*16.
__device__ __forceinline__ void stage16(const void* g, void* l) {
    typedef const __attribute__((address_space(1))) unsigned int gas_t;
    typedef __attribute__((address_space(3))) unsigned int las_t;
    __builtin_amdgcn_global_load_lds((gas_t*)(unsigned long long)g,
                                     (las_t*)(unsigned int)(unsigned long long)l,
                                     16, 0, 0);
}

// ---------------------------------------------------------------------------
// cvt_bf16: fp32 -> bf16, 8 elements/thread
// ---------------------------------------------------------------------------
__global__ __launch_bounds__(256) void cvt_bf16(const float* __restrict__ src,
                                                unsigned short* __restrict__ dst) {
    const size_t i = ((size_t)blockIdx.x * 256 + threadIdx.x) * 8;
    const float4 a = *(const float4*)(src + i);
    const float4 b = *(const float4*)(src + i + 4);
    ushort4 lo = pk_bf16x4(a.x, a.y, a.z, a.w);
    ushort4 hi = pk_bf16x4(b.x, b.y, b.z, b.w);
    us8 o;
    o[0] = lo.x; o[1] = lo.y; o[2] = lo.z; o[3] = lo.w;
    o[4] = hi.x; o[5] = hi.y; o[6] = hi.z; o[7] = hi.w;
    *(us8*)(dst + i) = o;
}

// ---------------------------------------------------------------------------
// mask_pack: int32 mask [B*S*S] -> bitmask [B*S*S/64] (bit j = chunk*64+j).
// ---------------------------------------------------------------------------
__global__ __launch_bounds__(256) void mask_pack(const int* __restrict__ mask,
                                                 unsigned long long* __restrict__ pm) {
    const int t = threadIdx.x;
    const size_t chunk = (size_t)blockIdx.x * 4 + (t >> 6);
    const int lane = t & 63;
    const int v = mask[chunk * 64 + lane];
    const unsigned long long b = __ballot(v != 0);
    if (lane == 0) pm[chunk] = b;
}

// ---------------------------------------------------------------------------
// NT GEMM, all-bf16 inputs (unchanged — verified).
// ---------------------------------------------------------------------------
template <int MODE>
__global__ __launch_bounds__(256) void gemm_nt(const unsigned short* __restrict__ A,
                                               const unsigned short* __restrict__ Wb,
                                               const float* __restrict__ bias,
                                               void* __restrict__ outp,
                                               float scale) {
    constexpr int K = DD;
    __shared__ __align__(16) unsigned short Ash[128][72];  // +8 pad
    __shared__ __align__(16) unsigned short Bsh[64][72];

    const int m0 = blockIdx.x * 128;
    const int n0 = blockIdx.y * 64;
    const int t = threadIdx.x;
    const int lane = t & 63, w = t >> 6;
    const int l15 = lane & 15, quad = lane >> 4;
    const int wm = (w >> 1) * 64, wn = (w & 1) * 32;

    f32x4 acc[4][2] = {};

    for (int k0 = 0; k0 < K; k0 += 64) {
        __syncthreads();
#pragma unroll
        for (int j = 0; j < 4; ++j) {              // A: 128x64 bf16
            const int v = t + j * 256;
            const int row = v >> 3, off = (v & 7) * 8;
            *(us8*)&Ash[row][off] = *(const us8*)&A[(size_t)(m0 + row) * K + k0 + off];
        }
#pragma unroll
        for (int j = 0; j < 2; ++j) {              // B: 64x64 bf16
            const int v = t + j * 256;
            const int row = v >> 3, off = (v & 7) * 8;
            *(us8*)&Bsh[row][off] = *(const us8*)&Wb[(size_t)(n0 + row) * K + k0 + off];
        }
        __syncthreads();

#pragma unroll
        for (int s = 0; s < 2; ++s) {
            bf16x8 af[4], bfr[2];
#pragma unroll
            for (int mi = 0; mi < 4; ++mi)
                af[mi] = *(const bf16x8*)&Ash[wm + mi * 16 + l15][s * 32 + quad * 8];
#pragma unroll
            for (int ni = 0; ni < 2; ++ni)
                bfr[ni] = *(const bf16x8*)&Bsh[wn + ni * 16 + l15][s * 32 + quad * 8];
#pragma unroll
            for (int mi = 0; mi < 4; ++mi)
#pragma unroll
                for (int ni = 0; ni < 2; ++ni)
                    acc[mi][ni] = mfma_bf16(af[mi], bfr[ni], acc[mi][ni]);
        }
    }

#pragma unroll
    for (int ni = 0; ni < 2; ++ni) {
        const int c = n0 + wn + ni * 16 + l15;
        const float bs = bias[c];
#pragma unroll
        for (int mi = 0; mi < 4; ++mi) {
#pragma unroll
            for (int r = 0; r < 4; ++r) {
                const int mrow = m0 + wm + mi * 16 + quad * 4 + r;
                const float val = (acc[mi][ni][r] + bs) * scale;
                if (MODE == 2) {
                    ((float*)outp)[(size_t)mrow * DD + c] = val;
                } else {
                    const int bi2 = mrow >> 11, si = mrow & (SS - 1);
                    const int hi2 = c >> 6, di = c & (DHH - 1);
                    unsigned short* o = (unsigned short*)outp;
                    if (MODE == 0)
                        o[((size_t)(bi2 * HH + hi2) * SS + si) * DHH + di] = f32_to_bf16(val);
                    else
                        o[((size_t)(bi2 * HH + hi2) * DHH + di) * SS + si] = f32_to_bf16(val);
                }
            }
        }
    }
}

// ---------------------------------------------------------------------------
// Flash attention v4: 8 waves (512 thr), 128 q-rows/block, 16 rows/wave.
//  - K/V double-buffered in LDS via global_load_lds (16B DMA), counted
//    vmcnt(3) + raw s_barrier: next tile's loads stay in flight across
//    barriers (T3/T4 minimal 2-phase).
//  - chunk-XOR swizzle (c ^= row&7, 16B chunks): DMA dest linear, global
//    SOURCE pre-swizzled (m173 pattern); fragment ds_read_b128 balanced
//    8 lanes / 4-bank group -> conflict-free.
//  - s_setprio(1) around MFMA clusters (T5).
// Per-tile math identical to the verified R3/R4 kernel.
// ---------------------------------------------------------------------------
__global__ __launch_bounds__(512, 4) void flash_attn(const unsigned short* __restrict__ qws,
                                                     const unsigned short* __restrict__ kws,
                                                     const unsigned short* __restrict__ vws,
                                                     const unsigned long long* __restrict__ pm,
                                                     unsigned short* __restrict__ ctx) {
    __shared__ __align__(16) unsigned short Ksh[2][64][64];   // [key][d], swizzled
    __shared__ __align__(16) unsigned short Vsh[2][64][64];   // [d][key], swizzled
    __shared__ __align__(16) unsigned short Psh[8][16][72];   // per-wave [q][key]

    constexpr int NQT = SS / 128;
    const int qt = blockIdx.x % NQT;
    const int bh = blockIdx.x / NQT;
    const int bi = bh / HH, hi = bh % HH;

    const int t = threadIdx.x;
    const int lane = t & 63, w = t >> 6;           // w in 0..7
    const int l15 = lane & 15, quad = lane >> 4;
    const int sh4 = quad * 4;
    const int xk = quad ^ (l15 & 7);               // swizzled chunk for fragment reads

    const unsigned short* qp = qws + (size_t)bh * SS * DHH;
    const unsigned short* kp = kws + (size_t)bh * SS * DHH;
    const unsigned short* vp = vws + (size_t)bh * DHH * SS;

    const int q_loc = qt * 128 + w * 16 + l15;
    const bf16x8 bq0 = *(const bf16x8*)(qp + (size_t)q_loc * DHH + quad * 8);
    const bf16x8 bq1 = *(const bf16x8*)(qp + (size_t)q_loc * DHH + 32 + quad * 8);
    const unsigned long long* pmrow = pm + ((size_t)bi * SS + q_loc) * (SS / 64);

    // staging source (pre-swizzled): lane l writes LDS chunk w*64+l linearly;
    // its content must be source chunk (row, c ^ (row&7)).
    const int srow = lane >> 3;            // row within wave's 8-row stripe
    const int scol = (lane & 7) ^ srow;    // pre-swizzled source chunk
    const unsigned short* kg = kp + (size_t)(w * 8 + srow) * DHH + scol * 8;
    const unsigned short* vg = vp + (size_t)(w * 8 + srow) * SS + scol * 8;

    f32x4 accO[4] = {};                    // O^T: d = 16i+quad*4+r, q = l15
    float m_run = -1e30f, l_run = 0.f;
    const float NEG_INF = -__builtin_inff();

    unsigned long long mcur = pmrow[0];
    stage16(kg, &Ksh[0][w * 8][0]);        // tile 0 in flight
    stage16(vg, &Vsh[0][w * 8][0]);

    constexpr int NT = SS / 64;
    for (int kt = 0; kt < NT; ++kt) {
        const int cur = kt & 1;
        unsigned long long mnxt = 0;
        if (kt < NT - 1) {
            mnxt = pmrow[kt + 1];                                        // VMEM op #1
            stage16(kg + (size_t)(kt + 1) * 64 * DHH, &Ksh[cur ^ 1][w * 8][0]); // #2
            stage16(vg + (size_t)(kt + 1) * 64,       &Vsh[cur ^ 1][w * 8][0]); // #3
            // wait own current-tile DMA (leave the 3 newest in flight)
            __asm__ volatile("s_waitcnt vmcnt(3)" ::: "memory");
        } else {
            __asm__ volatile("s_waitcnt vmcnt(0)" ::: "memory");
        }
        __builtin_amdgcn_s_barrier();          // everyone's current tile landed
        __builtin_amdgcn_sched_barrier(0);     // no LDS reads hoist above this

        const unsigned short* Kb = &Ksh[cur][0][0];
        const unsigned short* Vb = &Vsh[cur][0][0];

        bf16x8 ak0[4], ak1[4];
#pragma unroll
        for (int i = 0; i < 4; ++i) {
            ak0[i] = *(const bf16x8*)&Kb[(i * 16 + l15) * 64 + xk * 8];
            ak1[i] = *(const bf16x8*)&Kb[(i * 16 + l15) * 64 + (xk ^ 4) * 8];
        }

        const unsigned int mlo = ((unsigned int)mcur) >> sh4;
        const unsigned int mhi = ((unsigned int)(mcur >> 32)) >> sh4;

        // S^T: key = kt*64 + 16i + quad*4 + r, q = l15
        float sc[4][4];
        __builtin_amdgcn_s_setprio(1);
#pragma unroll
        for (int i = 0; i < 4; ++i) {
            f32x4 s4 = {};
            s4 = mfma_bf16(ak0[i], bq0, s4);
            s4 = mfma_bf16(ak1[i], bq1, s4);
            const unsigned int mw = (i & 2) ? mhi : mlo;
#pragma unroll
            for (int r = 0; r < 4; ++r)
                sc[i][r] = ((mw >> ((i & 1) * 16 + r)) & 1u) ? NEG_INF : s4[r];
        }
        __builtin_amdgcn_s_setprio(0);

        // issue V fragment reads early; latency hides under softmax VALU
        bf16x8 av0[4], av1[4];
#pragma unroll
        for (int i = 0; i < 4; ++i) {
            av0[i] = *(const bf16x8*)&Vb[(i * 16 + l15) * 64 + xk * 8];
            av1[i] = *(const bf16x8*)&Vb[(i * 16 + l15) * 64 + (xk ^ 4) * 8];
        }

        // online softmax for q = l15 (base-2; scores carry log2e)
        float tm = sc[0][0];
#pragma unroll
        for (int i = 0; i < 4; ++i)
#pragma unroll
            for (int r = 0; r < 4; ++r) tm = fmaxf(tm, sc[i][r]);
        tm = fmaxf(tm, __shfl_xor(tm, 16));
        tm = fmaxf(tm, __shfl_xor(tm, 32));
        const float mn = fmaxf(m_run, tm);
        const float alpha = __builtin_amdgcn_exp2f(m_run - mn);
        float rs = 0.f;
#pragma unroll
        for (int i = 0; i < 4; ++i)
#pragma unroll
            for (int r = 0; r < 4; ++r) {
                const float p = __builtin_amdgcn_exp2f(sc[i][r] - mn);
                sc[i][r] = p;
                rs += p;
            }
        rs += __shfl_xor(rs, 16);
        rs += __shfl_xor(rs, 32);
        l_run = l_run * alpha + rs;
        m_run = mn;
#pragma unroll
        for (int i = 0; i < 4; ++i) accO[i] *= alpha;

        // P store: lane's 4 consecutive keys -> one b64 per i (wave-private)
#pragma unroll
        for (int i = 0; i < 4; ++i)
            *(ushort4*)&Psh[w][l15][i * 16 + sh4] =
                pk_bf16x4(sc[i][0], sc[i][1], sc[i][2], sc[i][3]);
        __asm__ volatile("s_waitcnt lgkmcnt(0)" ::: "memory");  // wave-local RAW

        const bf16x8 p0 = *(const bf16x8*)&Psh[w][l15][quad * 8];
        const bf16x8 p1 = *(const bf16x8*)&Psh[w][l15][32 + quad * 8];
        __builtin_amdgcn_s_setprio(1);
#pragma unroll
        for (int i = 0; i < 4; ++i) {
            accO[i] = mfma_bf16(av0[i], p0, accO[i]);   // O^T[d][q]
            accO[i] = mfma_bf16(av1[i], p1, accO[i]);
        }
        __builtin_amdgcn_s_setprio(0);

        __builtin_amdgcn_sched_barrier(0);     // nothing sinks below this point
        __builtin_amdgcn_s_barrier();          // all reads of buf[cur] done
        __builtin_amdgcn_sched_barrier(0);     // next iter's VMEM stays below
        mcur = mnxt;
    }

    // epilogue
    const float inv = 1.0f / l_run;
    unsigned short* cb = ctx + ((size_t)(bi * SS) + q_loc) * DD + hi * DHH;
#pragma unroll
    for (int i = 0; i < 4; ++i)
        *(ushort4*)&cb[i * 16 + sh4] = pk_bf16x4(accO[i][0] * inv, accO[i][1] * inv,
                                                 accO[i][2] * inv, accO[i][3] * inv);
}

// ---------------------------------------------------------------------------
// score_h0 v2: head-0 raw masked scores (S^T scheme) + per-chunk online
// (m, l) stats. Grid: B * 32 q-tiles * 4 key-chunks; block = 64q x 512keys.
// ---------------------------------------------------------------------------
__global__ __launch_bounds__(256) void score_h0(const unsigned short* __restrict__ q0,
                                                const unsigned short* __restrict__ k0,
                                                const unsigned long long* __restrict__ pm,
                                                float* __restrict__ outp,
                                                float2* __restrict__ stats) {
    __shared__ __align__(16) unsigned short Ksh[64][72];

    const int kc = blockIdx.x & 3;             // key chunk (512 keys)
    const int qt = (blockIdx.x >> 2) & 31;     // q tile
    const int bi = blockIdx.x >> 7;            // batch

    const int t = threadIdx.x;
    const int lane = t & 63, w = t >> 6;
    const int l15 = lane & 15, quad = lane >> 4;
    const int sh4 = quad * 4;

    const int q = qt * 64 + w * 16 + l15;      // this lane's q row
    const unsigned short* qp = q0 + ((size_t)bi * SS + q) * DHH;
    const bf16x8 bq0 = *(const bf16x8*)(qp + quad * 8);
    const bf16x8 bq1 = *(const bf16x8*)(qp + 32 + quad * 8);

    const unsigned short* kp = k0 + (size_t)bi * SS * DHH;
    const unsigned long long* pmq = pm + ((size_t)bi * SS + q) * (SS / 64);
    float* orow = outp + ((size_t)bi * SS + q) * SS;

    float m_l = -1e30f, l_l = 0.f;

    for (int kt = 0; kt < 8; ++kt) {
        const int key0 = kc * 512 + kt * 64;
        __syncthreads();
#pragma unroll
        for (int hf = 0; hf < 2; ++hf) {
            const int v = t + hf * 256;
            const int row = v >> 3, off = (v & 7) * 8;
            *(us8*)&Ksh[row][off] = *(const us8*)(kp + (size_t)(key0 + row) * DHH + off);
        }
        __syncthreads();

        const unsigned long long m64 = pmq[kc * 8 + kt];
        const unsigned int mlo = ((unsigned int)m64) >> sh4;
        const unsigned int mhi = ((unsigned int)(m64 >> 32)) >> sh4;

        float sc[4][4];
        float lm = -1e30f;
#pragma unroll
        for (int i = 0; i < 4; ++i) {
            const bf16x8 ak0 = *(const bf16x8*)&Ksh[i * 16 + l15][quad * 8];
            const bf16x8 ak1 = *(const bf16x8*)&Ksh[i * 16 + l15][32 + quad * 8];
            f32x4 s4 = {};
            s4 = mfma_bf16(ak0, bq0, s4);
            s4 = mfma_bf16(ak1, bq1, s4);
            const unsigned int mw = (i & 2) ? mhi : mlo;
            float4 ov;
#pragma unroll
            for (int r = 0; r < 4; ++r) {
                const float s = ((mw >> ((i & 1) * 16 + r)) & 1u) ? -1e18f : s4[r];
                sc[i][r] = s;
                lm = fmaxf(lm, s);
            }
            ov.x = sc[i][0]; ov.y = sc[i][1]; ov.z = sc[i][2]; ov.w = sc[i][3];
            *(float4*)&orow[key0 + i * 16 + sh4] = ov;
        }

        // lane-local online update over this tile's 16 scores
        const float mn = fmaxf(m_l, lm);
        float rs = 0.f;
#pragma unroll
        for (int i = 0; i < 4; ++i)
#pragma unroll
            for (int r = 0; r < 4; ++r) rs += __builtin_amdgcn_exp2f(sc[i][r] - mn);
        l_l = l_l * __builtin_amdgcn_exp2f(m_l - mn) + rs;
        m_l = mn;
    }

    // merge the 4 quads owning this q-row (lanes l, l^16, l^32, l^48): LSE-merge
#pragma unroll
    for (int d = 16; d <= 32; d <<= 1) {
        const float mo = __shfl_xor(m_l, d);
        const float lo = __shfl_xor(l_l, d);
        const float mn = fmaxf(m_l, mo);
        l_l = l_l * __builtin_amdgcn_exp2f(m_l - mn) + lo * __builtin_amdgcn_exp2f(mo - mn);
        m_l = mn;
    }
    if (quad == 0) {
        float2 st; st.x = m_l; st.y = l_l;
        stats[((size_t)(bi * 4 + kc)) * SS + q] = st;
    }
}

// ---------------------------------------------------------------------------
// scale_h0: scores -> probs using per-chunk stats. One block per row,
// 8 elements/thread (pure stream). p = 2^(s - M) / L.
// ---------------------------------------------------------------------------
__global__ __launch_bounds__(256) void scale_h0(float* __restrict__ scores,
                                                const float2* __restrict__ stats) {
    const int bi = blockIdx.x >> 11;           // row = bi*S + si
    const int si = blockIdx.x & (SS - 1);
    const int t = threadIdx.x;

    // merge 4 chunk stats for this row
    float M = -1e30f, L = 0.f;
#pragma unroll
    for (int c = 0; c < 4; ++c) {
        const float2 st = stats[((size_t)(bi * 4 + c)) * SS + si];
        const float mn = fmaxf(M, st.x);
        L = L * __builtin_amdgcn_exp2f(M - mn) + st.y * __builtin_amdgcn_exp2f(st.x - mn);
        M = mn;
    }
    const float inv = 1.0f / L;

    float* row = scores + (size_t)blockIdx.x * SS;
    const int base = t * 8;
    float4 a = *(const float4*)&row[base];
    float4 b = *(const float4*)&row[base + 4];
    a.x = __builtin_amdgcn_exp2f(a.x - M) * inv;
    a.y = __builtin_amdgcn_exp2f(a.y - M) * inv;
    a.z = __builtin_amdgcn_exp2f(a.z - M) * inv;
    a.w = __builtin_amdgcn_exp2f(a.w - M) * inv;
    b.x = __builtin_amdgcn_exp2f(b.x - M) * inv;
    b.y = __builtin_amdgcn_exp2f(b.y - M) * inv;
    b.z = __builtin_amdgcn_exp2f(b.z - M) * inv;
    b.w = __builtin_amdgcn_exp2f(b.w - M) * inv;
    *(float4*)&row[base] = a;
    *(float4*)&row[base + 4] = b;
}

// ---------------------------------------------------------------------------
// inputs: 0 key, 1 value, 2 query, 3 mask, 4 Wk, 5 bk, 6 Wv, 7 bv,
//         8 Wq, 9 bq, 10 Wo, 11 bo
// d_out: output (B*S*D f32, 16 MB) ++ top_attn (B*S*S f32, 32 MB)
// d_ws (~2.13 MB): head-0 q/k (1 MB) + packed mask bits (1 MB) + stats (128 KB)
// ---------------------------------------------------------------------------
extern "C" void kernel_launch(void* const* d_in, const int* in_sizes, int n_in,
                              void* d_out, int out_size, void* d_ws, size_t ws_size,
                              hipStream_t stream) {
    const float* key_   = (const float*)d_in[0];
    const float* value_ = (const float*)d_in[1];
    const float* query_ = (const float*)d_in[2];
    const int*   mask_  = (const int*)d_in[3];
    const float* Wk = (const float*)d_in[4];
    const float* bk = (const float*)d_in[5];
    const float* Wv = (const float*)d_in[6];
    const float* bv = (const float*)d_in[7];
    const float* Wq = (const float*)d_in[8];
    const float* bq = (const float*)d_in[9];
    const float* Wo = (const float*)d_in[10];
    const float* bo = (const float*)d_in[11];

    constexpr size_t XS  = (size_t)BB * SS * DD;  // 4194304 elements
    constexpr size_t WSZ = (size_t)DD * DD;       // 1048576 elements

    float* out_f = (float*)d_out;
    unsigned short* scratch = (unsigned short*)(out_f + XS);
    unsigned short* qws = scratch;            // (B,H,S,DH)
    unsigned short* kws = qws + XS;           // (B,H,S,DH)
    unsigned short* vws = kws + XS;           // (B,H,DH,S)
    unsigned short* ctx = vws + XS;           // (B,S,D) — holds Wq/Wk/Wv bf16 pre-flash

    unsigned short* q0 = (unsigned short*)d_ws;             // [B][S][DH] head-0 q
    unsigned short* k0 = q0 + (size_t)BB * SS * DHH;        // [B][S][DH] head-0 k
    unsigned long long* pm = (unsigned long long*)(k0 + (size_t)BB * SS * DHH); // 1 MB
    float2* stats = (float2*)(pm + (size_t)BB * SS * (SS / 64));                // 128 KB

    // bf16 staging areas in dead regions
    unsigned short* Xq  = (unsigned short*)out_f;           // 8 MB
    unsigned short* Xk  = Xq + XS;                          // 8 MB
    unsigned short* Xv  = kws;                              // kws free till gemm-k
    unsigned short* Wqb = ctx;                              // ctx free till flash
    unsigned short* Wkb = Wqb + WSZ;
    unsigned short* Wvb = Wkb + WSZ;
    unsigned short* Wob = qws;                              // qws free after flash

    mask_pack<<<BB * SS * (SS / 64) / 4, 256, 0, stream>>>(mask_, pm);

    cvt_bf16<<<XS / 2048, 256, 0, stream>>>(query_, Xq);
    cvt_bf16<<<XS / 2048, 256, 0, stream>>>(key_,   Xk);
    cvt_bf16<<<XS / 2048, 256, 0, stream>>>(value_, Xv);
    cvt_bf16<<<WSZ / 2048, 256, 0, stream>>>(Wq, Wqb);
    cvt_bf16<<<WSZ / 2048, 256, 0, stream>>>(Wk, Wkb);
    cvt_bf16<<<WSZ / 2048, 256, 0, stream>>>(Wv, Wvb);

    // q scale = 1/sqrt(DH) * log2(e)  -> exp2-based softmax downstream
    const float qscale = 0.125f * 1.4426950408889634f;

    dim3 gg(BB * SS / 128, DD / 64);
    gemm_nt<0><<<gg, 256, 0, stream>>>(Xq, Wqb, bq, qws, qscale);
    gemm_nt<1><<<gg, 256, 0, stream>>>(Xv, Wvb, bv, vws, 1.0f);   // before gemm-k (Xv in kws)
    gemm_nt<0><<<gg, 256, 0, stream>>>(Xk, Wkb, bk, kws, 1.0f);

    // save head-0 q/k before the scratch region is clobbered at the end
    for (int b = 0; b < BB; ++b) {
        hipMemcpyAsync(q0 + (size_t)b * SS * DHH, qws + (size_t)(b * HH) * SS * DHH,
                       (size_t)SS * DHH * sizeof(unsigned short),
                       hipMemcpyDeviceToDevice, stream);
        hipMemcpyAsync(k0 + (size_t)b * SS * DHH, kws + (size_t)(b * HH) * SS * DHH,
                       (size_t)SS * DHH * sizeof(unsigned short),
                       hipMemcpyDeviceToDevice, stream);
    }

    flash_attn<<<BB * HH * (SS / 128), 512, 0, stream>>>(qws, kws, vws, pm, ctx);

    // qws is consumed; reuse it for Wo bf16, then the final GEMM
    cvt_bf16<<<WSZ / 2048, 256, 0, stream>>>(Wo, Wob);
    gemm_nt<2><<<gg, 256, 0, stream>>>(ctx, Wob, bo, out_f, 1.0f);

    // LAST: overwrite the scratch region with head-0 scores, then scale in place
    score_h0<<<BB * 32 * 4, 256, 0, stream>>>(q0, k0, pm, out_f + XS, stats);
    scale_h0<<<BB * SS, 256, 0, stream>>>(out_f + XS, stats);
}

// Round 2
// 343.425 us; speedup vs baseline: 1.0899x; 1.0342x over previous
//
#include <hip/hip_runtime.h>

// Problem constants: B=2, S=2048, D=1024, H=16, DH=64
constexpr int BB = 2, SS = 2048, DD = 1024, HH = 16, DHH = 64;

typedef __attribute__((ext_vector_type(4))) float f32x4;
typedef __attribute__((ext_vector_type(8))) __bf16 bf16x8;      // 4 VGPRs, MFMA A/B operand
typedef __attribute__((ext_vector_type(8))) unsigned short us8; // 16B staging vector

__device__ __forceinline__ unsigned short f32_to_bf16(float f) {
    unsigned int u = __float_as_uint(f);
    u += 0x7fffu + ((u >> 16) & 1u);   // round-to-nearest-even
    return (unsigned short)(u >> 16);
}

// packed f32x2 -> bf16x2 (RNE); gfx950 has v_cvt_pk_bf16_f32
__device__ __forceinline__ ushort2 pk_bf16(float a, float b) {
#if __has_builtin(__builtin_amdgcn_cvt_pk_bf16_f32)
    typedef __attribute__((ext_vector_type(2))) __bf16 bf16x2;
    bf16x2 r = __builtin_amdgcn_cvt_pk_bf16_f32(a, b);
    return *(ushort2*)&r;
#else
    ushort2 r; r.x = f32_to_bf16(a); r.y = f32_to_bf16(b); return r;
#endif
}
__device__ __forceinline__ ushort4 pk_bf16x4(float a, float b, float c, float d) {
    const ushort2 lo = pk_bf16(a, b), hi = pk_bf16(c, d);
    ushort4 r; r.x = lo.x; r.y = lo.y; r.z = hi.x; r.w = hi.y;
    return r;
}

__device__ __forceinline__ f32x4 mfma_bf16(bf16x8 a, bf16x8 b, f32x4 c) {
    return __builtin_amdgcn_mfma_f32_16x16x32_bf16(a, b, c, 0, 0, 0);
}

// async global->LDS DMA, 16B per lane. LDS dest = wave-uniform base + lane*16.
__device__ __forceinline__ void stage16(const void* g, void* l) {
    typedef const __attribute__((address_space(1))) unsigned int gas_t;
    typedef __attribute__((address_space(3))) unsigned int las_t;
    __builtin_amdgcn_global_load_lds((gas_t*)(unsigned long long)g,
                                     (las_t*)(unsigned int)(unsigned long long)l,
                                     16, 0, 0);
}

// ---------------------------------------------------------------------------
// cvt_bf16: fp32 -> bf16, 8 elements/thread
// ---------------------------------------------------------------------------
__global__ __launch_bounds__(256) void cvt_bf16(const float* __restrict__ src,
                                                unsigned short* __restrict__ dst) {
    const size_t i = ((size_t)blockIdx.x * 256 + threadIdx.x) * 8;
    const float4 a = *(const float4*)(src + i);
    const float4 b = *(const float4*)(src + i + 4);
    ushort4 lo = pk_bf16x4(a.x, a.y, a.z, a.w);
    ushort4 hi = pk_bf16x4(b.x, b.y, b.z, b.w);
    us8 o;
    o[0] = lo.x; o[1] = lo.y; o[2] = lo.z; o[3] = lo.w;
    o[4] = hi.x; o[5] = hi.y; o[6] = hi.z; o[7] = hi.w;
    *(us8*)(dst + i) = o;
}

// ---------------------------------------------------------------------------
// mask_pack: int32 mask [B*S*S] -> bitmask [B*S*S/64] (bit j = chunk*64+j).
// ---------------------------------------------------------------------------
__global__ __launch_bounds__(256) void mask_pack(const int* __restrict__ mask,
                                                 unsigned long long* __restrict__ pm) {
    const int t = threadIdx.x;
    const size_t chunk = (size_t)blockIdx.x * 4 + (t >> 6);
    const int lane = t & 63;
    const int v = mask[chunk * 64 + lane];
    const unsigned long long b = __ballot(v != 0);
    if (lane == 0) pm[chunk] = b;
}

// ---------------------------------------------------------------------------
// NT GEMM v2: 128x64 tile, BK=64, 4 waves.
//  - global_load_lds 16B DMA staging (6 ops/thread/K-step), double-buffered
//  - counted s_waitcnt vmcnt(6): next K-tile's DMA stays in flight across
//    both raw s_barriers (flash-v4 pattern, verified)
//  - chunk-XOR swizzle: LDS dest linear (DMA requirement), global SOURCE
//    pre-swizzled per lane, fragment reads apply the same XOR -> 2-way
//    bank aliasing only (free)
//  - s_setprio(1) around the MFMA cluster
// Epilogue / output mapping unchanged (verified).
// ---------------------------------------------------------------------------
template <int MODE>
__global__ __launch_bounds__(256) void gemm_nt(const unsigned short* __restrict__ A,
                                               const unsigned short* __restrict__ Wb,
                                               const float* __restrict__ bias,
                                               void* __restrict__ outp,
                                               float scale) {
    constexpr int K = DD;
    __shared__ __align__(16) unsigned short Ash[2][128][64];
    __shared__ __align__(16) unsigned short Bsh[2][64][64];

    const int m0 = blockIdx.x * 128;
    const int n0 = blockIdx.y * 64;
    const int t = threadIdx.x;
    const int lane = t & 63, w = t >> 6;
    const int l15 = lane & 15, quad = lane >> 4;
    const int wm = (w >> 1) * 64, wn = (w & 1) * 32;

    // staging source (pre-swizzled). Lane l of issue j fills LDS row
    // (stripe + j*8 + (l>>3)), chunk (l&7); content must be global chunk
    // (l&7) ^ row&7, and row&7 == l>>3 for every issue (j*8 ≡ 0 mod 8).
    const int srow = lane >> 3;                    // 0..7
    const int scol8 = ((lane & 7) ^ srow) * 8;     // pre-swizzled col (bf16 units)
    const unsigned short* Ag = A + (size_t)(m0 + w * 32 + srow) * K + scol8;
    const unsigned short* Bg = Wb + (size_t)(n0 + w * 16 + srow) * K + scol8;

    f32x4 acc[4][2] = {};

    // prologue: K-tile 0 -> buf 0 (6 DMA ops/thread)
#pragma unroll
    for (int j = 0; j < 4; ++j) stage16(Ag + (size_t)j * 8 * K, &Ash[0][w * 32 + j * 8][0]);
#pragma unroll
    for (int j = 0; j < 2; ++j) stage16(Bg + (size_t)j * 8 * K, &Bsh[0][w * 16 + j * 8][0]);

    for (int kk = 0; kk < K / 64; ++kk) {
        const int cur = kk & 1;
        if (kk < K / 64 - 1) {
            const size_t ko = (size_t)(kk + 1) * 64;
#pragma unroll
            for (int j = 0; j < 4; ++j)
                stage16(Ag + (size_t)j * 8 * K + ko, &Ash[cur ^ 1][w * 32 + j * 8][0]);
#pragma unroll
            for (int j = 0; j < 2; ++j)
                stage16(Bg + (size_t)j * 8 * K + ko, &Bsh[cur ^ 1][w * 16 + j * 8][0]);
            // drain current tile's 6 DMA ops; leave the 6 newest in flight
            __asm__ volatile("s_waitcnt vmcnt(6)" ::: "memory");
        } else {
            __asm__ volatile("s_waitcnt vmcnt(0)" ::: "memory");
        }
        __builtin_amdgcn_s_barrier();
        __builtin_amdgcn_sched_barrier(0);

        const unsigned short* Ab = &Ash[cur][0][0];
        const unsigned short* Bb = &Bsh[cur][0][0];

#pragma unroll
        for (int s = 0; s < 2; ++s) {
            const int ch = ((s * 4 + quad) ^ (l15 & 7)) * 8;   // swizzled read chunk
            bf16x8 af[4], bfr[2];
#pragma unroll
            for (int mi = 0; mi < 4; ++mi)
                af[mi] = *(const bf16x8*)&Ab[(wm + mi * 16 + l15) * 64 + ch];
#pragma unroll
            for (int ni = 0; ni < 2; ++ni)
                bfr[ni] = *(const bf16x8*)&Bb[(wn + ni * 16 + l15) * 64 + ch];
            __builtin_amdgcn_s_setprio(1);
#pragma unroll
            for (int mi = 0; mi < 4; ++mi)
#pragma unroll
                for (int ni = 0; ni < 2; ++ni)
                    acc[mi][ni] = mfma_bf16(af[mi], bfr[ni], acc[mi][ni]);
            __builtin_amdgcn_s_setprio(0);
        }
        __builtin_amdgcn_sched_barrier(0);
        __builtin_amdgcn_s_barrier();
        __builtin_amdgcn_sched_barrier(0);
    }

#pragma unroll
    for (int ni = 0; ni < 2; ++ni) {
        const int c = n0 + wn + ni * 16 + l15;
        const float bs = bias[c];
#pragma unroll
        for (int mi = 0; mi < 4; ++mi) {
#pragma unroll
            for (int r = 0; r < 4; ++r) {
                const int mrow = m0 + wm + mi * 16 + quad * 4 + r;
                const float val = (acc[mi][ni][r] + bs) * scale;
                if (MODE == 2) {
                    ((float*)outp)[(size_t)mrow * DD + c] = val;
                } else {
                    const int bi2 = mrow >> 11, si = mrow & (SS - 1);
                    const int hi2 = c >> 6, di = c & (DHH - 1);
                    unsigned short* o = (unsigned short*)outp;
                    if (MODE == 0)
                        o[((size_t)(bi2 * HH + hi2) * SS + si) * DHH + di] = f32_to_bf16(val);
                    else
                        o[((size_t)(bi2 * HH + hi2) * DHH + di) * SS + si] = f32_to_bf16(val);
                }
            }
        }
    }
}

// ---------------------------------------------------------------------------
// Flash attention v5: v4 + defer-max (T13).
// 8 waves (512 thr), 128 q-rows/block, 16 rows/wave; K/V double-buffered via
// global_load_lds + counted vmcnt(3); chunk-XOR swizzle; setprio on MFMA.
// ---------------------------------------------------------------------------
__global__ __launch_bounds__(512, 4) void flash_attn(const unsigned short* __restrict__ qws,
                                                     const unsigned short* __restrict__ kws,
                                                     const unsigned short* __restrict__ vws,
                                                     const unsigned long long* __restrict__ pm,
                                                     unsigned short* __restrict__ ctx) {
    __shared__ __align__(16) unsigned short Ksh[2][64][64];   // [key][d], swizzled
    __shared__ __align__(16) unsigned short Vsh[2][64][64];   // [d][key], swizzled
    __shared__ __align__(16) unsigned short Psh[8][16][72];   // per-wave [q][key]

    constexpr int NQT = SS / 128;
    const int qt = blockIdx.x % NQT;
    const int bh = blockIdx.x / NQT;
    const int bi = bh / HH, hi = bh % HH;

    const int t = threadIdx.x;
    const int lane = t & 63, w = t >> 6;           // w in 0..7
    const int l15 = lane & 15, quad = lane >> 4;
    const int sh4 = quad * 4;
    const int xk = quad ^ (l15 & 7);               // swizzled chunk for fragment reads

    const unsigned short* qp = qws + (size_t)bh * SS * DHH;
    const unsigned short* kp = kws + (size_t)bh * SS * DHH;
    const unsigned short* vp = vws + (size_t)bh * DHH * SS;

    const int q_loc = qt * 128 + w * 16 + l15;
    const bf16x8 bq0 = *(const bf16x8*)(qp + (size_t)q_loc * DHH + quad * 8);
    const bf16x8 bq1 = *(const bf16x8*)(qp + (size_t)q_loc * DHH + 32 + quad * 8);
    const unsigned long long* pmrow = pm + ((size_t)bi * SS + q_loc) * (SS / 64);

    // staging source (pre-swizzled): lane l writes LDS chunk w*64+l linearly;
    // its content must be source chunk (row, c ^ (row&7)).
    const int srow = lane >> 3;            // row within wave's 8-row stripe
    const int scol = (lane & 7) ^ srow;    // pre-swizzled source chunk
    const unsigned short* kg = kp + (size_t)(w * 8 + srow) * DHH + scol * 8;
    const unsigned short* vg = vp + (size_t)(w * 8 + srow) * SS + scol * 8;

    f32x4 accO[4] = {};                    // O^T: d = 16i+quad*4+r, q = l15
    float m_run = -1e30f, l_run = 0.f;
    const float NEG_INF = -__builtin_inff();

    unsigned long long mcur = pmrow[0];
    stage16(kg, &Ksh[0][w * 8][0]);        // tile 0 in flight
    stage16(vg, &Vsh[0][w * 8][0]);

    constexpr int NT = SS / 64;
    for (int kt = 0; kt < NT; ++kt) {
        const int cur = kt & 1;
        unsigned long long mnxt = 0;
        if (kt < NT - 1) {
            mnxt = pmrow[kt + 1];                                        // VMEM op #1
            stage16(kg + (size_t)(kt + 1) * 64 * DHH, &Ksh[cur ^ 1][w * 8][0]); // #2
            stage16(vg + (size_t)(kt + 1) * 64,       &Vsh[cur ^ 1][w * 8][0]); // #3
            // wait own current-tile DMA (leave the 3 newest in flight)
            __asm__ volatile("s_waitcnt vmcnt(3)" ::: "memory");
        } else {
            __asm__ volatile("s_waitcnt vmcnt(0)" ::: "memory");
        }
        __builtin_amdgcn_s_barrier();          // everyone's current tile landed
        __builtin_amdgcn_sched_barrier(0);     // no LDS reads hoist above this

        const unsigned short* Kb = &Ksh[cur][0][0];
        const unsigned short* Vb = &Vsh[cur][0][0];

        bf16x8 ak0[4], ak1[4];
#pragma unroll
        for (int i = 0; i < 4; ++i) {
            ak0[i] = *(const bf16x8*)&Kb[(i * 16 + l15) * 64 + xk * 8];
            ak1[i] = *(const bf16x8*)&Kb[(i * 16 + l15) * 64 + (xk ^ 4) * 8];
        }

        const unsigned int mlo = ((unsigned int)mcur) >> sh4;
        const unsigned int mhi = ((unsigned int)(mcur >> 32)) >> sh4;

        // S^T: key = kt*64 + 16i + quad*4 + r, q = l15
        float sc[4][4];
        __builtin_amdgcn_s_setprio(1);
#pragma unroll
        for (int i = 0; i < 4; ++i) {
            f32x4 s4 = {};
            s4 = mfma_bf16(ak0[i], bq0, s4);
            s4 = mfma_bf16(ak1[i], bq1, s4);
            const unsigned int mw = (i & 2) ? mhi : mlo;
#pragma unroll
            for (int r = 0; r < 4; ++r)
                sc[i][r] = ((mw >> ((i & 1) * 16 + r)) & 1u) ? NEG_INF : s4[r];
        }
        __builtin_amdgcn_s_setprio(0);

        // issue V fragment reads early; latency hides under softmax VALU
        bf16x8 av0[4], av1[4];
#pragma unroll
        for (int i = 0; i < 4; ++i) {
            av0[i] = *(const bf16x8*)&Vb[(i * 16 + l15) * 64 + xk * 8];
            av1[i] = *(const bf16x8*)&Vb[(i * 16 + l15) * 64 + (xk ^ 4) * 8];
        }

        // online softmax for q = l15 (base-2; scores carry log2e)
        float tm = sc[0][0];
#pragma unroll
        for (int i = 0; i < 4; ++i)
#pragma unroll
            for (int r = 0; r < 4; ++r) tm = fmaxf(tm, sc[i][r]);
        tm = fmaxf(tm, __shfl_xor(tm, 16));
        tm = fmaxf(tm, __shfl_xor(tm, 32));

        // defer-max (T13): if no q-row's tile-max exceeds m_run+8, keep the
        // old max -> skip accO rescale. P bounded by 2^8 (safe in bf16).
        const bool nodefer = !__all(tm <= m_run + 8.0f);
        const float mn = nodefer ? fmaxf(m_run, tm) : m_run;

        float rs = 0.f;
#pragma unroll
        for (int i = 0; i < 4; ++i)
#pragma unroll
            for (int r = 0; r < 4; ++r) {
                const float p = __builtin_amdgcn_exp2f(sc[i][r] - mn);
                sc[i][r] = p;
                rs += p;
            }
        rs += __shfl_xor(rs, 16);
        rs += __shfl_xor(rs, 32);

        if (nodefer) {                         // wave-uniform branch
            const float alpha = __builtin_amdgcn_exp2f(m_run - mn);
            l_run = l_run * alpha + rs;
            m_run = mn;
#pragma unroll
            for (int i = 0; i < 4; ++i) accO[i] *= alpha;
        } else {
            l_run += rs;
        }

        // P store: lane's 4 consecutive keys -> one b64 per i (wave-private)
#pragma unroll
        for (int i = 0; i < 4; ++i)
            *(ushort4*)&Psh[w][l15][i * 16 + sh4] =
                pk_bf16x4(sc[i][0], sc[i][1], sc[i][2], sc[i][3]);
        __asm__ volatile("s_waitcnt lgkmcnt(0)" ::: "memory");  // wave-local RAW

        const bf16x8 p0 = *(const bf16x8*)&Psh[w][l15][quad * 8];
        const bf16x8 p1 = *(const bf16x8*)&Psh[w][l15][32 + quad * 8];
        __builtin_amdgcn_s_setprio(1);
#pragma unroll
        for (int i = 0; i < 4; ++i) {
            accO[i] = mfma_bf16(av0[i], p0, accO[i]);   // O^T[d][q]
            accO[i] = mfma_bf16(av1[i], p1, accO[i]);
        }
        __builtin_amdgcn_s_setprio(0);

        __builtin_amdgcn_sched_barrier(0);     // nothing sinks below this point
        __builtin_amdgcn_s_barrier();          // all reads of buf[cur] done
        __builtin_amdgcn_sched_barrier(0);     // next iter's VMEM stays below
        mcur = mnxt;
    }

    // epilogue
    const float inv = 1.0f / l_run;
    unsigned short* cb = ctx + ((size_t)(bi * SS) + q_loc) * DD + hi * DHH;
#pragma unroll
    for (int i = 0; i < 4; ++i)
        *(ushort4*)&cb[i * 16 + sh4] = pk_bf16x4(accO[i][0] * inv, accO[i][1] * inv,
                                                 accO[i][2] * inv, accO[i][3] * inv);
}

// ---------------------------------------------------------------------------
// score_h0 v2: head-0 raw masked scores (S^T scheme) + per-chunk online
// (m, l) stats. Grid: B * 32 q-tiles * 4 key-chunks; block = 64q x 512keys.
// ---------------------------------------------------------------------------
__global__ __launch_bounds__(256) void score_h0(const unsigned short* __restrict__ q0,
                                                const unsigned short* __restrict__ k0,
                                                const unsigned long long* __restrict__ pm,
                                                float* __restrict__ outp,
                                                float2* __restrict__ stats) {
    __shared__ __align__(16) unsigned short Ksh[64][72];

    const int kc = blockIdx.x & 3;             // key chunk (512 keys)
    const int qt = (blockIdx.x >> 2) & 31;     // q tile
    const int bi = blockIdx.x >> 7;            // batch

    const int t = threadIdx.x;
    const int lane = t & 63, w = t >> 6;
    const int l15 = lane & 15, quad = lane >> 4;
    const int sh4 = quad * 4;

    const int q = qt * 64 + w * 16 + l15;      // this lane's q row
    const unsigned short* qp = q0 + ((size_t)bi * SS + q) * DHH;
    const bf16x8 bq0 = *(const bf16x8*)(qp + quad * 8);
    const bf16x8 bq1 = *(const bf16x8*)(qp + 32 + quad * 8);

    const unsigned short* kp = k0 + (size_t)bi * SS * DHH;
    const unsigned long long* pmq = pm + ((size_t)bi * SS + q) * (SS / 64);
    float* orow = outp + ((size_t)bi * SS + q) * SS;

    float m_l = -1e30f, l_l = 0.f;

    for (int kt = 0; kt < 8; ++kt) {
        const int key0 = kc * 512 + kt * 64;
        __syncthreads();
#pragma unroll
        for (int hf = 0; hf < 2; ++hf) {
            const int v = t + hf * 256;
            const int row = v >> 3, off = (v & 7) * 8;
            *(us8*)&Ksh[row][off] = *(const us8*)(kp + (size_t)(key0 + row) * DHH + off);
        }
        __syncthreads();

        const unsigned long long m64 = pmq[kc * 8 + kt];
        const unsigned int mlo = ((unsigned int)m64) >> sh4;
        const unsigned int mhi = ((unsigned int)(m64 >> 32)) >> sh4;

        float sc[4][4];
        float lm = -1e30f;
#pragma unroll
        for (int i = 0; i < 4; ++i) {
            const bf16x8 ak0 = *(const bf16x8*)&Ksh[i * 16 + l15][quad * 8];
            const bf16x8 ak1 = *(const bf16x8*)&Ksh[i * 16 + l15][32 + quad * 8];
            f32x4 s4 = {};
            s4 = mfma_bf16(ak0, bq0, s4);
            s4 = mfma_bf16(ak1, bq1, s4);
            const unsigned int mw = (i & 2) ? mhi : mlo;
            float4 ov;
#pragma unroll
            for (int r = 0; r < 4; ++r) {
                const float s = ((mw >> ((i & 1) * 16 + r)) & 1u) ? -1e18f : s4[r];
                sc[i][r] = s;
                lm = fmaxf(lm, s);
            }
            ov.x = sc[i][0]; ov.y = sc[i][1]; ov.z = sc[i][2]; ov.w = sc[i][3];
            *(float4*)&orow[key0 + i * 16 + sh4] = ov;
        }

        // lane-local online update over this tile's 16 scores
        const float mn = fmaxf(m_l, lm);
        float rs = 0.f;
#pragma unroll
        for (int i = 0; i < 4; ++i)
#pragma unroll
            for (int r = 0; r < 4; ++r) rs += __builtin_amdgcn_exp2f(sc[i][r] - mn);
        l_l = l_l * __builtin_amdgcn_exp2f(m_l - mn) + rs;
        m_l = mn;
    }

    // merge the 4 quads owning this q-row (lanes l, l^16, l^32, l^48): LSE-merge
#pragma unroll
    for (int d = 16; d <= 32; d <<= 1) {
        const float mo = __shfl_xor(m_l, d);
        const float lo = __shfl_xor(l_l, d);
        const float mn = fmaxf(m_l, mo);
        l_l = l_l * __builtin_amdgcn_exp2f(m_l - mn) + lo * __builtin_amdgcn_exp2f(mo - mn);
        m_l = mn;
    }
    if (quad == 0) {
        float2 st; st.x = m_l; st.y = l_l;
        stats[((size_t)(bi * 4 + kc)) * SS + q] = st;
    }
}

// ---------------------------------------------------------------------------
// scale_h0: scores -> probs using per-chunk stats. One block per row,
// 8 elements/thread (pure stream). p = 2^(s - M) / L.
// ---------------------------------------------------------------------------
__global__ __launch_bounds__(256) void scale_h0(float* __restrict__ scores,
                                                const float2* __restrict__ stats) {
    const int bi = blockIdx.x >> 11;           // row = bi*S + si
    const int si = blockIdx.x & (SS - 1);
    const int t = threadIdx.x;

    // merge 4 chunk stats for this row
    float M = -1e30f, L = 0.f;
#pragma unroll
    for (int c = 0; c < 4; ++c) {
        const float2 st = stats[((size_t)(bi * 4 + c)) * SS + si];
        const float mn = fmaxf(M, st.x);
        L = L * __builtin_amdgcn_exp2f(M - mn) + st.y * __builtin_amdgcn_exp2f(st.x - mn);
        M = mn;
    }
    const float inv = 1.0f / L;

    float* row = scores + (size_t)blockIdx.x * SS;
    const int base = t * 8;
    float4 a = *(const float4*)&row[base];
    float4 b = *(const float4*)&row[base + 4];
    a.x = __builtin_amdgcn_exp2f(a.x - M) * inv;
    a.y = __builtin_amdgcn_exp2f(a.y - M) * inv;
    a.z = __builtin_amdgcn_exp2f(a.z - M) * inv;
    a.w = __builtin_amdgcn_exp2f(a.w - M) * inv;
    b.x = __builtin_amdgcn_exp2f(b.x - M) * inv;
    b.y = __builtin_amdgcn_exp2f(b.y - M) * inv;
    b.z = __builtin_amdgcn_exp2f(b.z - M) * inv;
    b.w = __builtin_amdgcn_exp2f(b.w - M) * inv;
    *(float4*)&row[base] = a;
    *(float4*)&row[base + 4] = b;
}

// ---------------------------------------------------------------------------
// inputs: 0 key, 1 value, 2 query, 3 mask, 4 Wk, 5 bk, 6 Wv, 7 bv,
//         8 Wq, 9 bq, 10 Wo, 11 bo
// d_out: output (B*S*D f32, 16 MB) ++ top_attn (B*S*S f32, 32 MB)
// d_ws (~2.13 MB): head-0 q/k (1 MB) + packed mask bits (1 MB) + stats (128 KB)
// ---------------------------------------------------------------------------
extern "C" void kernel_launch(void* const* d_in, const int* in_sizes, int n_in,
                              void* d_out, int out_size, void* d_ws, size_t ws_size,
                              hipStream_t stream) {
    const float* key_   = (const float*)d_in[0];
    const float* value_ = (const float*)d_in[1];
    const float* query_ = (const float*)d_in[2];
    const int*   mask_  = (const int*)d_in[3];
    const float* Wk = (const float*)d_in[4];
    const float* bk = (const float*)d_in[5];
    const float* Wv = (const float*)d_in[6];
    const float* bv = (const float*)d_in[7];
    const float* Wq = (const float*)d_in[8];
    const float* bq = (const float*)d_in[9];
    const float* Wo = (const float*)d_in[10];
    const float* bo = (const float*)d_in[11];

    constexpr size_t XS  = (size_t)BB * SS * DD;  // 4194304 elements
    constexpr size_t WSZ = (size_t)DD * DD;       // 1048576 elements

    float* out_f = (float*)d_out;
    unsigned short* scratch = (unsigned short*)(out_f + XS);
    unsigned short* qws = scratch;            // (B,H,S,DH)
    unsigned short* kws = qws + XS;           // (B,H,S,DH)
    unsigned short* vws = kws + XS;           // (B,H,DH,S)
    unsigned short* ctx = vws + XS;           // (B,S,D) — holds Wq/Wk/Wv bf16 pre-flash

    unsigned short* q0 = (unsigned short*)d_ws;             // [B][S][DH] head-0 q
    unsigned short* k0 = q0 + (size_t)BB * SS * DHH;        // [B][S][DH] head-0 k
    unsigned long long* pm = (unsigned long long*)(k0 + (size_t)BB * SS * DHH); // 1 MB
    float2* stats = (float2*)(pm + (size_t)BB * SS * (SS / 64));                // 128 KB

    // bf16 staging areas in dead regions
    unsigned short* Xq  = (unsigned short*)out_f;           // 8 MB
    unsigned short* Xk  = Xq + XS;                          // 8 MB
    unsigned short* Xv  = kws;                              // kws free till gemm-k
    unsigned short* Wqb = ctx;                              // ctx free till flash
    unsigned short* Wkb = Wqb + WSZ;
    unsigned short* Wvb = Wkb + WSZ;
    unsigned short* Wob = qws;                              // qws free after flash

    mask_pack<<<BB * SS * (SS / 64) / 4, 256, 0, stream>>>(mask_, pm);

    cvt_bf16<<<XS / 2048, 256, 0, stream>>>(query_, Xq);
    cvt_bf16<<<XS / 2048, 256, 0, stream>>>(key_,   Xk);
    cvt_bf16<<<XS / 2048, 256, 0, stream>>>(value_, Xv);
    cvt_bf16<<<WSZ / 2048, 256, 0, stream>>>(Wq, Wqb);
    cvt_bf16<<<WSZ / 2048, 256, 0, stream>>>(Wk, Wkb);
    cvt_bf16<<<WSZ / 2048, 256, 0, stream>>>(Wv, Wvb);

    // q scale = 1/sqrt(DH) * log2(e)  -> exp2-based softmax downstream
    const float qscale = 0.125f * 1.4426950408889634f;

    dim3 gg(BB * SS / 128, DD / 64);
    gemm_nt<0><<<gg, 256, 0, stream>>>(Xq, Wqb, bq, qws, qscale);
    gemm_nt<1><<<gg, 256, 0, stream>>>(Xv, Wvb, bv, vws, 1.0f);   // before gemm-k (Xv in kws)
    gemm_nt<0><<<gg, 256, 0, stream>>>(Xk, Wkb, bk, kws, 1.0f);

    // save head-0 q/k before the scratch region is clobbered at the end
    for (int b = 0; b < BB; ++b) {
        hipMemcpyAsync(q0 + (size_t)b * SS * DHH, qws + (size_t)(b * HH) * SS * DHH,
                       (size_t)SS * DHH * sizeof(unsigned short),
                       hipMemcpyDeviceToDevice, stream);
        hipMemcpyAsync(k0 + (size_t)b * SS * DHH, kws + (size_t)(b * HH) * SS * DHH,
                       (size_t)SS * DHH * sizeof(unsigned short),
                       hipMemcpyDeviceToDevice, stream);
    }

    flash_attn<<<BB * HH * (SS / 128), 512, 0, stream>>>(qws, kws, vws, pm, ctx);

    // qws is consumed; reuse it for Wo bf16, then the final GEMM
    cvt_bf16<<<WSZ / 2048, 256, 0, stream>>>(Wo, Wob);
    gemm_nt<2><<<gg, 256, 0, stream>>>(ctx, Wob, bo, out_f, 1.0f);

    // LAST: overwrite the scratch region with head-0 scores, then scale in place
    score_h0<<<BB * 32 * 4, 256, 0, stream>>>(q0, k0, pm, out_f + XS, stats);
    scale_h0<<<BB * SS, 256, 0, stream>>>(out_f + XS, stats);
}

// Round 3
// 318.346 us; speedup vs baseline: 1.1758x; 1.0788x over previous
//
#include <hip/hip_runtime.h>

// Problem constants: B=2, S=2048, D=1024, H=16, DH=64
constexpr int BB = 2, SS = 2048, DD = 1024, HH = 16, DHH = 64;

typedef __attribute__((ext_vector_type(4))) float f32x4;
typedef __attribute__((ext_vector_type(8))) __bf16 bf16x8;      // 4 VGPRs, MFMA A/B operand
typedef __attribute__((ext_vector_type(8))) unsigned short us8; // 16B staging vector

__device__ __forceinline__ unsigned short f32_to_bf16(float f) {
    unsigned int u = __float_as_uint(f);
    u += 0x7fffu + ((u >> 16) & 1u);   // round-to-nearest-even
    return (unsigned short)(u >> 16);
}

// packed f32x2 -> bf16x2 (RNE); gfx950 has v_cvt_pk_bf16_f32
__device__ __forceinline__ ushort2 pk_bf16(float a, float b) {
#if __has_builtin(__builtin_amdgcn_cvt_pk_bf16_f32)
    typedef __attribute__((ext_vector_type(2))) __bf16 bf16x2;
    bf16x2 r = __builtin_amdgcn_cvt_pk_bf16_f32(a, b);
    return *(ushort2*)&r;
#else
    ushort2 r; r.x = f32_to_bf16(a); r.y = f32_to_bf16(b); return r;
#endif
}
__device__ __forceinline__ ushort4 pk_bf16x4(float a, float b, float c, float d) {
    const ushort2 lo = pk_bf16(a, b), hi = pk_bf16(c, d);
    ushort4 r; r.x = lo.x; r.y = lo.y; r.z = hi.x; r.w = hi.y;
    return r;
}

__device__ __forceinline__ f32x4 mfma_bf16(bf16x8 a, bf16x8 b, f32x4 c) {
    return __builtin_amdgcn_mfma_f32_16x16x32_bf16(a, b, c, 0, 0, 0);
}

// async global->LDS DMA, 16B per lane. LDS dest = wave-uniform base + lane*16.
__device__ __forceinline__ void stage16(const void* g, void* l) {
    typedef const __attribute__((address_space(1))) unsigned int gas_t;
    typedef __attribute__((address_space(3))) unsigned int las_t;
    __builtin_amdgcn_global_load_lds((gas_t*)(unsigned long long)g,
                                     (las_t*)(unsigned int)(unsigned long long)l,
                                     16, 0, 0);
}

// ---------------------------------------------------------------------------
// cvt_bf16: fp32 -> bf16, 8 elements/thread
// ---------------------------------------------------------------------------
__global__ __launch_bounds__(256) void cvt_bf16(const float* __restrict__ src,
                                                unsigned short* __restrict__ dst) {
    const size_t i = ((size_t)blockIdx.x * 256 + threadIdx.x) * 8;
    const float4 a = *(const float4*)(src + i);
    const float4 b = *(const float4*)(src + i + 4);
    ushort4 lo = pk_bf16x4(a.x, a.y, a.z, a.w);
    ushort4 hi = pk_bf16x4(b.x, b.y, b.z, b.w);
    us8 o;
    o[0] = lo.x; o[1] = lo.y; o[2] = lo.z; o[3] = lo.w;
    o[4] = hi.x; o[5] = hi.y; o[6] = hi.z; o[7] = hi.w;
    *(us8*)(dst + i) = o;
}

// ---------------------------------------------------------------------------
// mask_pack: int32 mask [B*S*S] -> bitmask [B*S*S/64] (bit j = chunk*64+j).
// ---------------------------------------------------------------------------
__global__ __launch_bounds__(256) void mask_pack(const int* __restrict__ mask,
                                                 unsigned long long* __restrict__ pm) {
    const int t = threadIdx.x;
    const size_t chunk = (size_t)blockIdx.x * 4 + (t >> 6);
    const int lane = t & 63;
    const int v = mask[chunk * 64 + lane];
    const unsigned long long b = __ballot(v != 0);
    if (lane == 0) pm[chunk] = b;
}

// ---------------------------------------------------------------------------
// NT GEMM v3: 128x64 tile, BK=64, 4 waves; 1D grid with XCD-chunked swizzle
// (n-tile fast within a chunk -> each XCD keeps 4 A-panels + full weights
// in its private L2). DMA staging / counted vmcnt / swizzle unchanged.
// ---------------------------------------------------------------------------
template <int MODE>
__global__ __launch_bounds__(256) void gemm_nt(const unsigned short* __restrict__ A,
                                               const unsigned short* __restrict__ Wb,
                                               const float* __restrict__ bias,
                                               void* __restrict__ outp,
                                               float scale) {
    constexpr int K = DD;
    __shared__ __align__(16) unsigned short Ash[2][128][64];
    __shared__ __align__(16) unsigned short Bsh[2][64][64];

    // 512 blocks: bijective XCD chunking (512 % 8 == 0), n fast within chunk
    const int id = blockIdx.x;
    const int nid = (id & 7) * 64 + (id >> 3);
    const int n0 = (nid & 15) * 64;
    const int m0 = (nid >> 4) * 128;

    const int t = threadIdx.x;
    const int lane = t & 63, w = t >> 6;
    const int l15 = lane & 15, quad = lane >> 4;
    const int wm = (w >> 1) * 64, wn = (w & 1) * 32;

    // staging source (pre-swizzled). Lane l of issue j fills LDS row
    // (stripe + j*8 + (l>>3)), chunk (l&7); content must be global chunk
    // (l&7) ^ row&7, and row&7 == l>>3 for every issue (j*8 ≡ 0 mod 8).
    const int srow = lane >> 3;                    // 0..7
    const int scol8 = ((lane & 7) ^ srow) * 8;     // pre-swizzled col (bf16 units)
    const unsigned short* Ag = A + (size_t)(m0 + w * 32 + srow) * K + scol8;
    const unsigned short* Bg = Wb + (size_t)(n0 + w * 16 + srow) * K + scol8;

    f32x4 acc[4][2] = {};

    // prologue: K-tile 0 -> buf 0 (6 DMA ops/thread)
#pragma unroll
    for (int j = 0; j < 4; ++j) stage16(Ag + (size_t)j * 8 * K, &Ash[0][w * 32 + j * 8][0]);
#pragma unroll
    for (int j = 0; j < 2; ++j) stage16(Bg + (size_t)j * 8 * K, &Bsh[0][w * 16 + j * 8][0]);

    for (int kk = 0; kk < K / 64; ++kk) {
        const int cur = kk & 1;
        if (kk < K / 64 - 1) {
            const size_t ko = (size_t)(kk + 1) * 64;
#pragma unroll
            for (int j = 0; j < 4; ++j)
                stage16(Ag + (size_t)j * 8 * K + ko, &Ash[cur ^ 1][w * 32 + j * 8][0]);
#pragma unroll
            for (int j = 0; j < 2; ++j)
                stage16(Bg + (size_t)j * 8 * K + ko, &Bsh[cur ^ 1][w * 16 + j * 8][0]);
            // drain current tile's 6 DMA ops; leave the 6 newest in flight
            __asm__ volatile("s_waitcnt vmcnt(6)" ::: "memory");
        } else {
            __asm__ volatile("s_waitcnt vmcnt(0)" ::: "memory");
        }
        __builtin_amdgcn_s_barrier();
        __builtin_amdgcn_sched_barrier(0);

        const unsigned short* Ab = &Ash[cur][0][0];
        const unsigned short* Bb = &Bsh[cur][0][0];

#pragma unroll
        for (int s = 0; s < 2; ++s) {
            const int ch = ((s * 4 + quad) ^ (l15 & 7)) * 8;   // swizzled read chunk
            bf16x8 af[4], bfr[2];
#pragma unroll
            for (int mi = 0; mi < 4; ++mi)
                af[mi] = *(const bf16x8*)&Ab[(wm + mi * 16 + l15) * 64 + ch];
#pragma unroll
            for (int ni = 0; ni < 2; ++ni)
                bfr[ni] = *(const bf16x8*)&Bb[(wn + ni * 16 + l15) * 64 + ch];
            __builtin_amdgcn_s_setprio(1);
#pragma unroll
            for (int mi = 0; mi < 4; ++mi)
#pragma unroll
                for (int ni = 0; ni < 2; ++ni)
                    acc[mi][ni] = mfma_bf16(af[mi], bfr[ni], acc[mi][ni]);
            __builtin_amdgcn_s_setprio(0);
        }
        __builtin_amdgcn_sched_barrier(0);
        __builtin_amdgcn_s_barrier();
        __builtin_amdgcn_sched_barrier(0);
    }

#pragma unroll
    for (int ni = 0; ni < 2; ++ni) {
        const int c = n0 + wn + ni * 16 + l15;
        const float bs = bias[c];
#pragma unroll
        for (int mi = 0; mi < 4; ++mi) {
#pragma unroll
            for (int r = 0; r < 4; ++r) {
                const int mrow = m0 + wm + mi * 16 + quad * 4 + r;
                const float val = (acc[mi][ni][r] + bs) * scale;
                if (MODE == 2) {
                    ((float*)outp)[(size_t)mrow * DD + c] = val;
                } else {
                    const int bi2 = mrow >> 11, si = mrow & (SS - 1);
                    const int hi2 = c >> 6, di = c & (DHH - 1);
                    unsigned short* o = (unsigned short*)outp;
                    if (MODE == 0)
                        o[((size_t)(bi2 * HH + hi2) * SS + si) * DHH + di] = f32_to_bf16(val);
                    else
                        o[((size_t)(bi2 * HH + hi2) * DHH + di) * SS + si] = f32_to_bf16(val);
                }
            }
        }
    }
}

// ---------------------------------------------------------------------------
// Flash attention v6: v5 + head-0 (M,L) stats export + XCD-chunked swizzle.
// 8 waves (512 thr), 128 q-rows/block, 16 rows/wave; K/V double-buffered via
// global_load_lds + counted vmcnt(3); chunk-XOR swizzle; setprio on MFMA;
// defer-max (T13).
// ---------------------------------------------------------------------------
__global__ __launch_bounds__(512, 4) void flash_attn(const unsigned short* __restrict__ qws,
                                                     const unsigned short* __restrict__ kws,
                                                     const unsigned short* __restrict__ vws,
                                                     const unsigned long long* __restrict__ pm,
                                                     unsigned short* __restrict__ ctx,
                                                     float2* __restrict__ stats) {
    __shared__ __align__(16) unsigned short Ksh[2][64][64];   // [key][d], swizzled
    __shared__ __align__(16) unsigned short Vsh[2][64][64];   // [d][key], swizzled
    __shared__ __align__(16) unsigned short Psh[8][16][72];   // per-wave [q][key]

    constexpr int NQT = SS / 128;                  // 16
    // 512 blocks: XCD-chunked (bijective): each XCD gets 4 full bh groups
    const int id = blockIdx.x;
    const int nid = (id & 7) * 64 + (id >> 3);
    const int qt = nid % NQT;
    const int bh = nid / NQT;
    const int bi = bh / HH, hi = bh % HH;

    const int t = threadIdx.x;
    const int lane = t & 63, w = t >> 6;           // w in 0..7
    const int l15 = lane & 15, quad = lane >> 4;
    const int sh4 = quad * 4;
    const int xk = quad ^ (l15 & 7);               // swizzled chunk for fragment reads

    const unsigned short* qp = qws + (size_t)bh * SS * DHH;
    const unsigned short* kp = kws + (size_t)bh * SS * DHH;
    const unsigned short* vp = vws + (size_t)bh * DHH * SS;

    const int q_loc = qt * 128 + w * 16 + l15;
    const bf16x8 bq0 = *(const bf16x8*)(qp + (size_t)q_loc * DHH + quad * 8);
    const bf16x8 bq1 = *(const bf16x8*)(qp + (size_t)q_loc * DHH + 32 + quad * 8);
    const unsigned long long* pmrow = pm + ((size_t)bi * SS + q_loc) * (SS / 64);

    // staging source (pre-swizzled): lane l writes LDS chunk w*64+l linearly;
    // its content must be source chunk (row, c ^ (row&7)).
    const int srow = lane >> 3;            // row within wave's 8-row stripe
    const int scol = (lane & 7) ^ srow;    // pre-swizzled source chunk
    const unsigned short* kg = kp + (size_t)(w * 8 + srow) * DHH + scol * 8;
    const unsigned short* vg = vp + (size_t)(w * 8 + srow) * SS + scol * 8;

    f32x4 accO[4] = {};                    // O^T: d = 16i+quad*4+r, q = l15
    float m_run = -1e30f, l_run = 0.f;
    const float NEG_INF = -__builtin_inff();

    unsigned long long mcur = pmrow[0];
    stage16(kg, &Ksh[0][w * 8][0]);        // tile 0 in flight
    stage16(vg, &Vsh[0][w * 8][0]);

    constexpr int NT = SS / 64;
    for (int kt = 0; kt < NT; ++kt) {
        const int cur = kt & 1;
        unsigned long long mnxt = 0;
        if (kt < NT - 1) {
            mnxt = pmrow[kt + 1];                                        // VMEM op #1
            stage16(kg + (size_t)(kt + 1) * 64 * DHH, &Ksh[cur ^ 1][w * 8][0]); // #2
            stage16(vg + (size_t)(kt + 1) * 64,       &Vsh[cur ^ 1][w * 8][0]); // #3
            // wait own current-tile DMA (leave the 3 newest in flight)
            __asm__ volatile("s_waitcnt vmcnt(3)" ::: "memory");
        } else {
            __asm__ volatile("s_waitcnt vmcnt(0)" ::: "memory");
        }
        __builtin_amdgcn_s_barrier();          // everyone's current tile landed
        __builtin_amdgcn_sched_barrier(0);     // no LDS reads hoist above this

        const unsigned short* Kb = &Ksh[cur][0][0];
        const unsigned short* Vb = &Vsh[cur][0][0];

        bf16x8 ak0[4], ak1[4];
#pragma unroll
        for (int i = 0; i < 4; ++i) {
            ak0[i] = *(const bf16x8*)&Kb[(i * 16 + l15) * 64 + xk * 8];
            ak1[i] = *(const bf16x8*)&Kb[(i * 16 + l15) * 64 + (xk ^ 4) * 8];
        }

        const unsigned int mlo = ((unsigned int)mcur) >> sh4;
        const unsigned int mhi = ((unsigned int)(mcur >> 32)) >> sh4;

        // S^T: key = kt*64 + 16i + quad*4 + r, q = l15
        float sc[4][4];
        __builtin_amdgcn_s_setprio(1);
#pragma unroll
        for (int i = 0; i < 4; ++i) {
            f32x4 s4 = {};
            s4 = mfma_bf16(ak0[i], bq0, s4);
            s4 = mfma_bf16(ak1[i], bq1, s4);
            const unsigned int mw = (i & 2) ? mhi : mlo;
#pragma unroll
            for (int r = 0; r < 4; ++r)
                sc[i][r] = ((mw >> ((i & 1) * 16 + r)) & 1u) ? NEG_INF : s4[r];
        }
        __builtin_amdgcn_s_setprio(0);

        // issue V fragment reads early; latency hides under softmax VALU
        bf16x8 av0[4], av1[4];
#pragma unroll
        for (int i = 0; i < 4; ++i) {
            av0[i] = *(const bf16x8*)&Vb[(i * 16 + l15) * 64 + xk * 8];
            av1[i] = *(const bf16x8*)&Vb[(i * 16 + l15) * 64 + (xk ^ 4) * 8];
        }

        // online softmax for q = l15 (base-2; scores carry log2e)
        float tm = sc[0][0];
#pragma unroll
        for (int i = 0; i < 4; ++i)
#pragma unroll
            for (int r = 0; r < 4; ++r) tm = fmaxf(tm, sc[i][r]);
        tm = fmaxf(tm, __shfl_xor(tm, 16));
        tm = fmaxf(tm, __shfl_xor(tm, 32));

        // defer-max (T13): if no q-row's tile-max exceeds m_run+8, keep the
        // old max -> skip accO rescale. P bounded by 2^8 (safe in bf16).
        const bool nodefer = !__all(tm <= m_run + 8.0f);
        const float mn = nodefer ? fmaxf(m_run, tm) : m_run;

        float rs = 0.f;
#pragma unroll
        for (int i = 0; i < 4; ++i)
#pragma unroll
            for (int r = 0; r < 4; ++r) {
                const float p = __builtin_amdgcn_exp2f(sc[i][r] - mn);
                sc[i][r] = p;
                rs += p;
            }
        rs += __shfl_xor(rs, 16);
        rs += __shfl_xor(rs, 32);

        if (nodefer) {                         // wave-uniform branch
            const float alpha = __builtin_amdgcn_exp2f(m_run - mn);
            l_run = l_run * alpha + rs;
            m_run = mn;
#pragma unroll
            for (int i = 0; i < 4; ++i) accO[i] *= alpha;
        } else {
            l_run += rs;
        }

        // P store: lane's 4 consecutive keys -> one b64 per i (wave-private)
#pragma unroll
        for (int i = 0; i < 4; ++i)
            *(ushort4*)&Psh[w][l15][i * 16 + sh4] =
                pk_bf16x4(sc[i][0], sc[i][1], sc[i][2], sc[i][3]);
        __asm__ volatile("s_waitcnt lgkmcnt(0)" ::: "memory");  // wave-local RAW

        const bf16x8 p0 = *(const bf16x8*)&Psh[w][l15][quad * 8];
        const bf16x8 p1 = *(const bf16x8*)&Psh[w][l15][32 + quad * 8];
        __builtin_amdgcn_s_setprio(1);
#pragma unroll
        for (int i = 0; i < 4; ++i) {
            accO[i] = mfma_bf16(av0[i], p0, accO[i]);   // O^T[d][q]
            accO[i] = mfma_bf16(av1[i], p1, accO[i]);
        }
        __builtin_amdgcn_s_setprio(0);

        __builtin_amdgcn_sched_barrier(0);     // nothing sinks below this point
        __builtin_amdgcn_s_barrier();          // all reads of buf[cur] done
        __builtin_amdgcn_sched_barrier(0);     // next iter's VMEM stays below
        mcur = mnxt;
    }

    // epilogue
    const float inv = 1.0f / l_run;
    unsigned short* cb = ctx + ((size_t)(bi * SS) + q_loc) * DD + hi * DHH;
#pragma unroll
    for (int i = 0; i < 4; ++i)
        *(ushort4*)&cb[i * 16 + sh4] = pk_bf16x4(accO[i][0] * inv, accO[i][1] * inv,
                                                 accO[i][2] * inv, accO[i][3] * inv);

    // head-0: export softmax stats (M, L). p = exp2(s - M)/L is exact even
    // with deferred M (both offsets cancel). All quads hold identical copies.
    if (hi == 0 && quad == 0) {
        float2 st; st.x = m_run; st.y = l_run;
        stats[(size_t)bi * SS + q_loc] = st;
    }
}

// ---------------------------------------------------------------------------
// prob_h0: head-0 final attention probabilities in ONE pass, using flash's
// (M, L) stats. Same bf16 operands + MFMA order as flash -> bit-identical
// scores. Masked -> exactly 0 (matches exp(-1e18 - M) underflow in ref).
// Grid: B * 32 q-tiles * 4 key-chunks; block = 64q x 512keys.
// ---------------------------------------------------------------------------
__global__ __launch_bounds__(256) void prob_h0(const unsigned short* __restrict__ q0,
                                               const unsigned short* __restrict__ k0,
                                               const unsigned long long* __restrict__ pm,
                                               const float2* __restrict__ stats,
                                               float* __restrict__ outp) {
    __shared__ __align__(16) unsigned short Ksh[64][72];

    const int kc = blockIdx.x & 3;             // key chunk (512 keys)
    const int qt = (blockIdx.x >> 2) & 31;     // q tile
    const int bi = blockIdx.x >> 7;            // batch

    const int t = threadIdx.x;
    const int lane = t & 63, w = t >> 6;
    const int l15 = lane & 15, quad = lane >> 4;
    const int sh4 = quad * 4;

    const int q = qt * 64 + w * 16 + l15;      // this lane's q row
    const unsigned short* qp = q0 + ((size_t)bi * SS + q) * DHH;
    const bf16x8 bq0 = *(const bf16x8*)(qp + quad * 8);
    const bf16x8 bq1 = *(const bf16x8*)(qp + 32 + quad * 8);

    const unsigned short* kp = k0 + (size_t)bi * SS * DHH;
    const unsigned long long* pmq = pm + ((size_t)bi * SS + q) * (SS / 64);
    float* orow = outp + ((size_t)bi * SS + q) * SS;

    const float2 st = stats[(size_t)bi * SS + q];
    const float M = st.x;
    const float invL = 1.0f / st.y;

    for (int kt = 0; kt < 8; ++kt) {
        const int key0 = kc * 512 + kt * 64;
        __syncthreads();
#pragma unroll
        for (int hf = 0; hf < 2; ++hf) {
            const int v = t + hf * 256;
            const int row = v >> 3, off = (v & 7) * 8;
            *(us8*)&Ksh[row][off] = *(const us8*)(kp + (size_t)(key0 + row) * DHH + off);
        }
        __syncthreads();

        const unsigned long long m64 = pmq[kc * 8 + kt];
        const unsigned int mlo = ((unsigned int)m64) >> sh4;
        const unsigned int mhi = ((unsigned int)(m64 >> 32)) >> sh4;

#pragma unroll
        for (int i = 0; i < 4; ++i) {
            const bf16x8 ak0 = *(const bf16x8*)&Ksh[i * 16 + l15][quad * 8];
            const bf16x8 ak1 = *(const bf16x8*)&Ksh[i * 16 + l15][32 + quad * 8];
            f32x4 s4 = {};
            s4 = mfma_bf16(ak0, bq0, s4);
            s4 = mfma_bf16(ak1, bq1, s4);
            const unsigned int mw = (i & 2) ? mhi : mlo;
            float4 ov;
#pragma unroll
            for (int r = 0; r < 4; ++r) {
                const float p = __builtin_amdgcn_exp2f(s4[r] - M) * invL;
                ((float*)&ov)[r] = ((mw >> ((i & 1) * 16 + r)) & 1u) ? 0.0f : p;
            }
            *(float4*)&orow[key0 + i * 16 + sh4] = ov;
        }
    }
}

// ---------------------------------------------------------------------------
// inputs: 0 key, 1 value, 2 query, 3 mask, 4 Wk, 5 bk, 6 Wv, 7 bv,
//         8 Wq, 9 bq, 10 Wo, 11 bo
// d_out: output (B*S*D f32, 16 MB) ++ top_attn (B*S*S f32, 32 MB)
// d_ws (~2.13 MB): head-0 q/k (1 MB) + packed mask bits (1 MB) + stats (32 KB)
// ---------------------------------------------------------------------------
extern "C" void kernel_launch(void* const* d_in, const int* in_sizes, int n_in,
                              void* d_out, int out_size, void* d_ws, size_t ws_size,
                              hipStream_t stream) {
    const float* key_   = (const float*)d_in[0];
    const float* value_ = (const float*)d_in[1];
    const float* query_ = (const float*)d_in[2];
    const int*   mask_  = (const int*)d_in[3];
    const float* Wk = (const float*)d_in[4];
    const float* bk = (const float*)d_in[5];
    const float* Wv = (const float*)d_in[6];
    const float* bv = (const float*)d_in[7];
    const float* Wq = (const float*)d_in[8];
    const float* bq = (const float*)d_in[9];
    const float* Wo = (const float*)d_in[10];
    const float* bo = (const float*)d_in[11];

    constexpr size_t XS  = (size_t)BB * SS * DD;  // 4194304 elements
    constexpr size_t WSZ = (size_t)DD * DD;       // 1048576 elements

    float* out_f = (float*)d_out;
    unsigned short* scratch = (unsigned short*)(out_f + XS);
    unsigned short* qws = scratch;            // (B,H,S,DH)
    unsigned short* kws = qws + XS;           // (B,H,S,DH)
    unsigned short* vws = kws + XS;           // (B,H,DH,S)
    unsigned short* ctx = vws + XS;           // (B,S,D) — holds Wq/Wk/Wv bf16 pre-flash

    unsigned short* q0 = (unsigned short*)d_ws;             // [B][S][DH] head-0 q
    unsigned short* k0 = q0 + (size_t)BB * SS * DHH;        // [B][S][DH] head-0 k
    unsigned long long* pm = (unsigned long long*)(k0 + (size_t)BB * SS * DHH); // 1 MB
    float2* stats = (float2*)(pm + (size_t)BB * SS * (SS / 64));                // 32 KB

    // bf16 staging areas in dead regions
    unsigned short* Xq  = (unsigned short*)out_f;           // 8 MB
    unsigned short* Xk  = Xq + XS;                          // 8 MB
    unsigned short* Xv  = kws;                              // kws free till gemm-k
    unsigned short* Wqb = ctx;                              // ctx free till flash
    unsigned short* Wkb = Wqb + WSZ;
    unsigned short* Wvb = Wkb + WSZ;
    unsigned short* Wob = qws;                              // qws free after flash

    mask_pack<<<BB * SS * (SS / 64) / 4, 256, 0, stream>>>(mask_, pm);

    cvt_bf16<<<XS / 2048, 256, 0, stream>>>(query_, Xq);
    cvt_bf16<<<XS / 2048, 256, 0, stream>>>(key_,   Xk);
    cvt_bf16<<<XS / 2048, 256, 0, stream>>>(value_, Xv);
    cvt_bf16<<<WSZ / 2048, 256, 0, stream>>>(Wq, Wqb);
    cvt_bf16<<<WSZ / 2048, 256, 0, stream>>>(Wk, Wkb);
    cvt_bf16<<<WSZ / 2048, 256, 0, stream>>>(Wv, Wvb);

    // q scale = 1/sqrt(DH) * log2(e)  -> exp2-based softmax downstream
    const float qscale = 0.125f * 1.4426950408889634f;

    gemm_nt<0><<<512, 256, 0, stream>>>(Xq, Wqb, bq, qws, qscale);
    gemm_nt<1><<<512, 256, 0, stream>>>(Xv, Wvb, bv, vws, 1.0f);   // before gemm-k (Xv in kws)
    gemm_nt<0><<<512, 256, 0, stream>>>(Xk, Wkb, bk, kws, 1.0f);

    // save head-0 q/k before the scratch region is clobbered at the end
    for (int b = 0; b < BB; ++b) {
        hipMemcpyAsync(q0 + (size_t)b * SS * DHH, qws + (size_t)(b * HH) * SS * DHH,
                       (size_t)SS * DHH * sizeof(unsigned short),
                       hipMemcpyDeviceToDevice, stream);
        hipMemcpyAsync(k0 + (size_t)b * SS * DHH, kws + (size_t)(b * HH) * SS * DHH,
                       (size_t)SS * DHH * sizeof(unsigned short),
                       hipMemcpyDeviceToDevice, stream);
    }

    flash_attn<<<BB * HH * (SS / 128), 512, 0, stream>>>(qws, kws, vws, pm, ctx, stats);

    // qws is consumed; reuse it for Wo bf16, then the final GEMM
    cvt_bf16<<<WSZ / 2048, 256, 0, stream>>>(Wo, Wob);
    gemm_nt<2><<<512, 256, 0, stream>>>(ctx, Wob, bo, out_f, 1.0f);

    // LAST: single pass writes final head-0 probabilities over the scratch
    // region using flash's (M, L) stats
    prob_h0<<<BB * 32 * 4, 256, 0, stream>>>(q0, k0, pm, stats, out_f + XS);
}

// Round 4
// 302.915 us; speedup vs baseline: 1.2357x; 1.0509x over previous
//
#include <hip/hip_runtime.h>

// Problem constants: B=2, S=2048, D=1024, H=16, DH=64
constexpr int BB = 2, SS = 2048, DD = 1024, HH = 16, DHH = 64;

typedef __attribute__((ext_vector_type(4))) float f32x4;
typedef __attribute__((ext_vector_type(8))) __bf16 bf16x8;      // 4 VGPRs, MFMA A/B operand
typedef __attribute__((ext_vector_type(8))) unsigned short us8; // 16B staging vector

__device__ __forceinline__ unsigned short f32_to_bf16(float f) {
    unsigned int u = __float_as_uint(f);
    u += 0x7fffu + ((u >> 16) & 1u);   // round-to-nearest-even
    return (unsigned short)(u >> 16);
}

// packed f32x2 -> bf16x2 (RNE); gfx950 has v_cvt_pk_bf16_f32
__device__ __forceinline__ ushort2 pk_bf16(float a, float b) {
#if __has_builtin(__builtin_amdgcn_cvt_pk_bf16_f32)
    typedef __attribute__((ext_vector_type(2))) __bf16 bf16x2;
    bf16x2 r = __builtin_amdgcn_cvt_pk_bf16_f32(a, b);
    return *(ushort2*)&r;
#else
    ushort2 r; r.x = f32_to_bf16(a); r.y = f32_to_bf16(b); return r;
#endif
}
__device__ __forceinline__ ushort4 pk_bf16x4(float a, float b, float c, float d) {
    const ushort2 lo = pk_bf16(a, b), hi = pk_bf16(c, d);
    ushort4 r; r.x = lo.x; r.y = lo.y; r.z = hi.x; r.w = hi.y;
    return r;
}

__device__ __forceinline__ f32x4 mfma_bf16(bf16x8 a, bf16x8 b, f32x4 c) {
    return __builtin_amdgcn_mfma_f32_16x16x32_bf16(a, b, c, 0, 0, 0);
}

// async global->LDS DMA, 16B per lane. LDS dest = wave-uniform base + lane*16.
__device__ __forceinline__ void stage16(const void* g, void* l) {
    typedef const __attribute__((address_space(1))) unsigned int gas_t;
    typedef __attribute__((address_space(3))) unsigned int las_t;
    __builtin_amdgcn_global_load_lds((gas_t*)(unsigned long long)g,
                                     (las_t*)(unsigned int)(unsigned long long)l,
                                     16, 0, 0);
}

// ---------------------------------------------------------------------------
// cvt helper: fp32 -> bf16, 8 elements/thread, one 2048-element block `blk`
// ---------------------------------------------------------------------------
__device__ __forceinline__ void cvt_block(const float* __restrict__ src,
                                          unsigned short* __restrict__ dst, int blk) {
    const size_t i = ((size_t)blk * 256 + threadIdx.x) * 8;
    const float4 a = *(const float4*)(src + i);
    const float4 b = *(const float4*)(src + i + 4);
    ushort4 lo = pk_bf16x4(a.x, a.y, a.z, a.w);
    ushort4 hi = pk_bf16x4(b.x, b.y, b.z, b.w);
    us8 o;
    o[0] = lo.x; o[1] = lo.y; o[2] = lo.z; o[3] = lo.w;
    o[4] = hi.x; o[5] = hi.y; o[6] = hi.z; o[7] = hi.w;
    *(us8*)(dst + i) = o;
}

// standalone cvt (used for Wo after flash)
__global__ __launch_bounds__(256) void cvt_bf16(const float* __restrict__ src,
                                                unsigned short* __restrict__ dst) {
    cvt_block(src, dst, blockIdx.x);
}

// ---------------------------------------------------------------------------
// prep: ALL pre-gemm prep in one launch.
//   blocks [0,6144):    cvt query/key/value f32 -> bf16 (2048 blocks each)
//   blocks [6144,7680): cvt Wq/Wk/Wv (512 blocks each)
//   blocks [7680,15872): mask pack (8192 blocks x 16 chunks)
// ---------------------------------------------------------------------------
__global__ __launch_bounds__(256) void prep(const float* __restrict__ q,
                                            const float* __restrict__ k,
                                            const float* __restrict__ v,
                                            const float* __restrict__ Wq,
                                            const float* __restrict__ Wk,
                                            const float* __restrict__ Wv,
                                            unsigned short* __restrict__ Xq,
                                            unsigned short* __restrict__ Xk,
                                            unsigned short* __restrict__ Xv,
                                            unsigned short* __restrict__ Wqb,
                                            unsigned short* __restrict__ Wkb,
                                            unsigned short* __restrict__ Wvb,
                                            const int* __restrict__ mask,
                                            unsigned long long* __restrict__ pm) {
    const int id = blockIdx.x;
    if (id < 6144) {
        const int sel = id >> 11, blk = id & 2047;
        cvt_block(sel == 0 ? q : (sel == 1 ? k : v),
                  sel == 0 ? Xq : (sel == 1 ? Xk : Xv), blk);
    } else if (id < 7680) {
        const int wid = id - 6144;
        const int sel = wid >> 9, blk = wid & 511;
        cvt_block(sel == 0 ? Wq : (sel == 1 ? Wk : Wv),
                  sel == 0 ? Wqb : (sel == 1 ? Wkb : Wvb), blk);
    } else {
        const int mid = id - 7680;
        const int t = threadIdx.x, lane = t & 63;
#pragma unroll
        for (int it = 0; it < 4; ++it) {
            const size_t chunk = (size_t)mid * 16 + it * 4 + (t >> 6);
            const int val = mask[chunk * 64 + lane];
            const unsigned long long b = __ballot(val != 0);
            if (lane == 0) pm[chunk] = b;
        }
    }
}

// ---------------------------------------------------------------------------
// NT GEMM body (verified R2/R3 structure): 128x64 tile, BK=64, 4 waves.
// global_load_lds DMA staging, double-buffered, counted vmcnt(6), chunk-XOR
// swizzle (linear DMA dest + pre-swizzled global source + swizzled reads),
// setprio around MFMA. `nid` is the pre-swizzled block id in [0,512).
// mode: 0 = bf16 out (B,H,S,DH) [+ optional head-0 copy], 1 = bf16 out
// (B,H,DH,S), 2 = f32 out (B,S,D).
// ---------------------------------------------------------------------------
__device__ __forceinline__ void gemm_body(int mode,
                                          const unsigned short* __restrict__ A,
                                          const unsigned short* __restrict__ Wb,
                                          const float* __restrict__ bias,
                                          void* __restrict__ outp,
                                          float scale, int nid,
                                          unsigned short* __restrict__ h0) {
    constexpr int K = DD;
    __shared__ __align__(16) unsigned short Ash[2][128][64];
    __shared__ __align__(16) unsigned short Bsh[2][64][64];

    const int n0 = (nid & 15) * 64;
    const int m0 = (nid >> 4) * 128;

    const int t = threadIdx.x;
    const int lane = t & 63, w = t >> 6;
    const int l15 = lane & 15, quad = lane >> 4;
    const int wm = (w >> 1) * 64, wn = (w & 1) * 32;

    // staging source (pre-swizzled); see R2 notes.
    const int srow = lane >> 3;                    // 0..7
    const int scol8 = ((lane & 7) ^ srow) * 8;     // pre-swizzled col (bf16 units)
    const unsigned short* Ag = A + (size_t)(m0 + w * 32 + srow) * K + scol8;
    const unsigned short* Bg = Wb + (size_t)(n0 + w * 16 + srow) * K + scol8;

    f32x4 acc[4][2] = {};

    // prologue: K-tile 0 -> buf 0 (6 DMA ops/thread)
#pragma unroll
    for (int j = 0; j < 4; ++j) stage16(Ag + (size_t)j * 8 * K, &Ash[0][w * 32 + j * 8][0]);
#pragma unroll
    for (int j = 0; j < 2; ++j) stage16(Bg + (size_t)j * 8 * K, &Bsh[0][w * 16 + j * 8][0]);

    for (int kk = 0; kk < K / 64; ++kk) {
        const int cur = kk & 1;
        if (kk < K / 64 - 1) {
            const size_t ko = (size_t)(kk + 1) * 64;
#pragma unroll
            for (int j = 0; j < 4; ++j)
                stage16(Ag + (size_t)j * 8 * K + ko, &Ash[cur ^ 1][w * 32 + j * 8][0]);
#pragma unroll
            for (int j = 0; j < 2; ++j)
                stage16(Bg + (size_t)j * 8 * K + ko, &Bsh[cur ^ 1][w * 16 + j * 8][0]);
            // drain current tile's 6 DMA ops; leave the 6 newest in flight
            __asm__ volatile("s_waitcnt vmcnt(6)" ::: "memory");
        } else {
            __asm__ volatile("s_waitcnt vmcnt(0)" ::: "memory");
        }
        __builtin_amdgcn_s_barrier();
        __builtin_amdgcn_sched_barrier(0);

        const unsigned short* Ab = &Ash[cur][0][0];
        const unsigned short* Bb = &Bsh[cur][0][0];

#pragma unroll
        for (int s = 0; s < 2; ++s) {
            const int ch = ((s * 4 + quad) ^ (l15 & 7)) * 8;   // swizzled read chunk
            bf16x8 af[4], bfr[2];
#pragma unroll
            for (int mi = 0; mi < 4; ++mi)
                af[mi] = *(const bf16x8*)&Ab[(wm + mi * 16 + l15) * 64 + ch];
#pragma unroll
            for (int ni = 0; ni < 2; ++ni)
                bfr[ni] = *(const bf16x8*)&Bb[(wn + ni * 16 + l15) * 64 + ch];
            __builtin_amdgcn_s_setprio(1);
#pragma unroll
            for (int mi = 0; mi < 4; ++mi)
#pragma unroll
                for (int ni = 0; ni < 2; ++ni)
                    acc[mi][ni] = mfma_bf16(af[mi], bfr[ni], acc[mi][ni]);
            __builtin_amdgcn_s_setprio(0);
        }
        __builtin_amdgcn_sched_barrier(0);
        __builtin_amdgcn_s_barrier();
        __builtin_amdgcn_sched_barrier(0);
    }

#pragma unroll
    for (int ni = 0; ni < 2; ++ni) {
        const int c = n0 + wn + ni * 16 + l15;
        const float bs = bias[c];
#pragma unroll
        for (int mi = 0; mi < 4; ++mi) {
#pragma unroll
            for (int r = 0; r < 4; ++r) {
                const int mrow = m0 + wm + mi * 16 + quad * 4 + r;
                const float val = (acc[mi][ni][r] + bs) * scale;
                if (mode == 2) {
                    ((float*)outp)[(size_t)mrow * DD + c] = val;
                } else {
                    const int bi2 = mrow >> 11, si = mrow & (SS - 1);
                    const int hi2 = c >> 6, di = c & (DHH - 1);
                    unsigned short* o = (unsigned short*)outp;
                    const unsigned short v16 = f32_to_bf16(val);
                    if (mode == 0) {
                        o[((size_t)(bi2 * HH + hi2) * SS + si) * DHH + di] = v16;
                        if (h0 != nullptr && hi2 == 0)
                            h0[((size_t)bi2 * SS + si) * DHH + di] = v16;  // head-0 copy
                    } else {
                        o[((size_t)(bi2 * HH + hi2) * DHH + di) * SS + si] = v16;
                    }
                }
            }
        }
    }
}

// fused Q + V projection: 1024 blocks (512 each), 3 blocks/CU resident.
__global__ __launch_bounds__(256) void gemm_qv(const unsigned short* __restrict__ Xq,
                                               const unsigned short* __restrict__ Wqb,
                                               const float* __restrict__ bq,
                                               unsigned short* __restrict__ qws,
                                               float qscale,
                                               unsigned short* __restrict__ q0,
                                               const unsigned short* __restrict__ Xv,
                                               const unsigned short* __restrict__ Wvb,
                                               const float* __restrict__ bv,
                                               unsigned short* __restrict__ vws) {
    const int id = blockIdx.x;
    const int gid = id >> 9, id9 = id & 511;
    const int nid = (id9 & 7) * 64 + (id9 >> 3);           // XCD-chunked, bijective
    gemm_body(gid, gid ? Xv : Xq, gid ? Wvb : Wqb, gid ? bv : bq,
              gid ? (void*)vws : (void*)qws, gid ? 1.0f : qscale, nid,
              gid ? nullptr : q0);
}

// single-gemm wrapper (K projection with head-0 export; output projection)
template <int MODE>
__global__ __launch_bounds__(256) void gemm_one(const unsigned short* __restrict__ A,
                                                const unsigned short* __restrict__ Wb,
                                                const float* __restrict__ bias,
                                                void* __restrict__ outp,
                                                float scale,
                                                unsigned short* __restrict__ h0) {
    const int id = blockIdx.x;
    const int nid = (id & 7) * 64 + (id >> 3);             // XCD-chunked, bijective
    gemm_body(MODE, A, Wb, bias, outp, scale, nid, h0);
}

// ---------------------------------------------------------------------------
// Flash attention v6 (verified R3): 8 waves, 128 q-rows/block, 16 rows/wave;
// K/V double-buffered via global_load_lds + counted vmcnt(3); chunk-XOR
// swizzle; setprio on MFMA; defer-max (T13); head-0 (M,L) stats export;
// XCD-chunked block swizzle.
// ---------------------------------------------------------------------------
__global__ __launch_bounds__(512, 4) void flash_attn(const unsigned short* __restrict__ qws,
                                                     const unsigned short* __restrict__ kws,
                                                     const unsigned short* __restrict__ vws,
                                                     const unsigned long long* __restrict__ pm,
                                                     unsigned short* __restrict__ ctx,
                                                     float2* __restrict__ stats) {
    __shared__ __align__(16) unsigned short Ksh[2][64][64];   // [key][d], swizzled
    __shared__ __align__(16) unsigned short Vsh[2][64][64];   // [d][key], swizzled
    __shared__ __align__(16) unsigned short Psh[8][16][72];   // per-wave [q][key]

    constexpr int NQT = SS / 128;                  // 16
    const int id = blockIdx.x;
    const int nid = (id & 7) * 64 + (id >> 3);
    const int qt = nid % NQT;
    const int bh = nid / NQT;
    const int bi = bh / HH, hi = bh % HH;

    const int t = threadIdx.x;
    const int lane = t & 63, w = t >> 6;           // w in 0..7
    const int l15 = lane & 15, quad = lane >> 4;
    const int sh4 = quad * 4;
    const int xk = quad ^ (l15 & 7);               // swizzled chunk for fragment reads

    const unsigned short* qp = qws + (size_t)bh * SS * DHH;
    const unsigned short* kp = kws + (size_t)bh * SS * DHH;
    const unsigned short* vp = vws + (size_t)bh * DHH * SS;

    const int q_loc = qt * 128 + w * 16 + l15;
    const bf16x8 bq0 = *(const bf16x8*)(qp + (size_t)q_loc * DHH + quad * 8);
    const bf16x8 bq1 = *(const bf16x8*)(qp + (size_t)q_loc * DHH + 32 + quad * 8);
    const unsigned long long* pmrow = pm + ((size_t)bi * SS + q_loc) * (SS / 64);

    // staging source (pre-swizzled): lane l writes LDS chunk w*64+l linearly;
    // its content must be source chunk (row, c ^ (row&7)).
    const int srow = lane >> 3;            // row within wave's 8-row stripe
    const int scol = (lane & 7) ^ srow;    // pre-swizzled source chunk
    const unsigned short* kg = kp + (size_t)(w * 8 + srow) * DHH + scol * 8;
    const unsigned short* vg = vp + (size_t)(w * 8 + srow) * SS + scol * 8;

    f32x4 accO[4] = {};                    // O^T: d = 16i+quad*4+r, q = l15
    float m_run = -1e30f, l_run = 0.f;
    const float NEG_INF = -__builtin_inff();

    unsigned long long mcur = pmrow[0];
    stage16(kg, &Ksh[0][w * 8][0]);        // tile 0 in flight
    stage16(vg, &Vsh[0][w * 8][0]);

    constexpr int NT = SS / 64;
    for (int kt = 0; kt < NT; ++kt) {
        const int cur = kt & 1;
        unsigned long long mnxt = 0;
        if (kt < NT - 1) {
            mnxt = pmrow[kt + 1];                                        // VMEM op #1
            stage16(kg + (size_t)(kt + 1) * 64 * DHH, &Ksh[cur ^ 1][w * 8][0]); // #2
            stage16(vg + (size_t)(kt + 1) * 64,       &Vsh[cur ^ 1][w * 8][0]); // #3
            // wait own current-tile DMA (leave the 3 newest in flight)
            __asm__ volatile("s_waitcnt vmcnt(3)" ::: "memory");
        } else {
            __asm__ volatile("s_waitcnt vmcnt(0)" ::: "memory");
        }
        __builtin_amdgcn_s_barrier();          // everyone's current tile landed
        __builtin_amdgcn_sched_barrier(0);     // no LDS reads hoist above this

        const unsigned short* Kb = &Ksh[cur][0][0];
        const unsigned short* Vb = &Vsh[cur][0][0];

        bf16x8 ak0[4], ak1[4];
#pragma unroll
        for (int i = 0; i < 4; ++i) {
            ak0[i] = *(const bf16x8*)&Kb[(i * 16 + l15) * 64 + xk * 8];
            ak1[i] = *(const bf16x8*)&Kb[(i * 16 + l15) * 64 + (xk ^ 4) * 8];
        }

        const unsigned int mlo = ((unsigned int)mcur) >> sh4;
        const unsigned int mhi = ((unsigned int)(mcur >> 32)) >> sh4;

        // S^T: key = kt*64 + 16i + quad*4 + r, q = l15
        float sc[4][4];
        __builtin_amdgcn_s_setprio(1);
#pragma unroll
        for (int i = 0; i < 4; ++i) {
            f32x4 s4 = {};
            s4 = mfma_bf16(ak0[i], bq0, s4);
            s4 = mfma_bf16(ak1[i], bq1, s4);
            const unsigned int mw = (i & 2) ? mhi : mlo;
#pragma unroll
            for (int r = 0; r < 4; ++r)
                sc[i][r] = ((mw >> ((i & 1) * 16 + r)) & 1u) ? NEG_INF : s4[r];
        }
        __builtin_amdgcn_s_setprio(0);

        // issue V fragment reads early; latency hides under softmax VALU
        bf16x8 av0[4], av1[4];
#pragma unroll
        for (int i = 0; i < 4; ++i) {
            av0[i] = *(const bf16x8*)&Vb[(i * 16 + l15) * 64 + xk * 8];
            av1[i] = *(const bf16x8*)&Vb[(i * 16 + l15) * 64 + (xk ^ 4) * 8];
        }

        // online softmax for q = l15 (base-2; scores carry log2e)
        float tm = sc[0][0];
#pragma unroll
        for (int i = 0; i < 4; ++i)
#pragma unroll
            for (int r = 0; r < 4; ++r) tm = fmaxf(tm, sc[i][r]);
        tm = fmaxf(tm, __shfl_xor(tm, 16));
        tm = fmaxf(tm, __shfl_xor(tm, 32));

        // defer-max (T13): if no q-row's tile-max exceeds m_run+8, keep the
        // old max -> skip accO rescale. P bounded by 2^8 (safe in bf16).
        const bool nodefer = !__all(tm <= m_run + 8.0f);
        const float mn = nodefer ? fmaxf(m_run, tm) : m_run;

        float rs = 0.f;
#pragma unroll
        for (int i = 0; i < 4; ++i)
#pragma unroll
            for (int r = 0; r < 4; ++r) {
                const float p = __builtin_amdgcn_exp2f(sc[i][r] - mn);
                sc[i][r] = p;
                rs += p;
            }
        rs += __shfl_xor(rs, 16);
        rs += __shfl_xor(rs, 32);

        if (nodefer) {                         // wave-uniform branch
            const float alpha = __builtin_amdgcn_exp2f(m_run - mn);
            l_run = l_run * alpha + rs;
            m_run = mn;
#pragma unroll
            for (int i = 0; i < 4; ++i) accO[i] *= alpha;
        } else {
            l_run += rs;
        }

        // P store: lane's 4 consecutive keys -> one b64 per i (wave-private)
#pragma unroll
        for (int i = 0; i < 4; ++i)
            *(ushort4*)&Psh[w][l15][i * 16 + sh4] =
                pk_bf16x4(sc[i][0], sc[i][1], sc[i][2], sc[i][3]);
        __asm__ volatile("s_waitcnt lgkmcnt(0)" ::: "memory");  // wave-local RAW

        const bf16x8 p0 = *(const bf16x8*)&Psh[w][l15][quad * 8];
        const bf16x8 p1 = *(const bf16x8*)&Psh[w][l15][32 + quad * 8];
        __builtin_amdgcn_s_setprio(1);
#pragma unroll
        for (int i = 0; i < 4; ++i) {
            accO[i] = mfma_bf16(av0[i], p0, accO[i]);   // O^T[d][q]
            accO[i] = mfma_bf16(av1[i], p1, accO[i]);
        }
        __builtin_amdgcn_s_setprio(0);

        __builtin_amdgcn_sched_barrier(0);     // nothing sinks below this point
        __builtin_amdgcn_s_barrier();          // all reads of buf[cur] done
        __builtin_amdgcn_sched_barrier(0);     // next iter's VMEM stays below
        mcur = mnxt;
    }

    // epilogue
    const float inv = 1.0f / l_run;
    unsigned short* cb = ctx + ((size_t)(bi * SS) + q_loc) * DD + hi * DHH;
#pragma unroll
    for (int i = 0; i < 4; ++i)
        *(ushort4*)&cb[i * 16 + sh4] = pk_bf16x4(accO[i][0] * inv, accO[i][1] * inv,
                                                 accO[i][2] * inv, accO[i][3] * inv);

    // head-0: export softmax stats (M, L). p = exp2(s - M)/L is exact even
    // with deferred M (both offsets cancel). All quads hold identical copies.
    if (hi == 0 && quad == 0) {
        float2 st; st.x = m_run; st.y = l_run;
        stats[(size_t)bi * SS + q_loc] = st;
    }
}

// ---------------------------------------------------------------------------
// prob_h0: head-0 final attention probabilities in ONE pass, using flash's
// (M, L) stats. Same bf16 operands + MFMA order as flash -> bit-identical
// scores. Masked -> exactly 0.
// Grid: 512 blocks (B * 32 q-tiles * 8 key-chunks of 256), 2 blocks/CU.
// ---------------------------------------------------------------------------
__global__ __launch_bounds__(256) void prob_h0(const unsigned short* __restrict__ q0,
                                               const unsigned short* __restrict__ k0,
                                               const unsigned long long* __restrict__ pm,
                                               const float2* __restrict__ stats,
                                               float* __restrict__ outp) {
    __shared__ __align__(16) unsigned short Ksh[64][72];

    const int id = blockIdx.x;
    const int nid = (id & 7) * 64 + (id >> 3);     // XCD-chunked, bijective
    const int kc = nid & 7;                        // key chunk (256 keys)
    const int qt = (nid >> 3) & 31;                // q tile
    const int bi = nid >> 8;                       // batch

    const int t = threadIdx.x;
    const int lane = t & 63, w = t >> 6;
    const int l15 = lane & 15, quad = lane >> 4;
    const int sh4 = quad * 4;

    const int q = qt * 64 + w * 16 + l15;      // this lane's q row
    const unsigned short* qp = q0 + ((size_t)bi * SS + q) * DHH;
    const bf16x8 bq0 = *(const bf16x8*)(qp + quad * 8);
    const bf16x8 bq1 = *(const bf16x8*)(qp + 32 + quad * 8);

    const unsigned short* kp = k0 + (size_t)bi * SS * DHH;
    const unsigned long long* pmq = pm + ((size_t)bi * SS + q) * (SS / 64);
    float* orow = outp + ((size_t)bi * SS + q) * SS;

    const float2 st = stats[(size_t)bi * SS + q];
    const float M = st.x;
    const float invL = 1.0f / st.y;

    for (int kt = 0; kt < 4; ++kt) {
        const int key0 = kc * 256 + kt * 64;
        __syncthreads();
#pragma unroll
        for (int hf = 0; hf < 2; ++hf) {
            const int v = t + hf * 256;
            const int row = v >> 3, off = (v & 7) * 8;
            *(us8*)&Ksh[row][off] = *(const us8*)(kp + (size_t)(key0 + row) * DHH + off);
        }
        __syncthreads();

        const unsigned long long m64 = pmq[kc * 4 + kt];
        const unsigned int mlo = ((unsigned int)m64) >> sh4;
        const unsigned int mhi = ((unsigned int)(m64 >> 32)) >> sh4;

#pragma unroll
        for (int i = 0; i < 4; ++i) {
            const bf16x8 ak0 = *(const bf16x8*)&Ksh[i * 16 + l15][quad * 8];
            const bf16x8 ak1 = *(const bf16x8*)&Ksh[i * 16 + l15][32 + quad * 8];
            f32x4 s4 = {};
            s4 = mfma_bf16(ak0, bq0, s4);
            s4 = mfma_bf16(ak1, bq1, s4);
            const unsigned int mw = (i & 2) ? mhi : mlo;
            float4 ov;
#pragma unroll
            for (int r = 0; r < 4; ++r) {
                const float p = __builtin_amdgcn_exp2f(s4[r] - M) * invL;
                ((float*)&ov)[r] = ((mw >> ((i & 1) * 16 + r)) & 1u) ? 0.0f : p;
            }
            *(float4*)&orow[key0 + i * 16 + sh4] = ov;
        }
    }
}

// ---------------------------------------------------------------------------
// inputs: 0 key, 1 value, 2 query, 3 mask, 4 Wk, 5 bk, 6 Wv, 7 bv,
//         8 Wq, 9 bq, 10 Wo, 11 bo
// d_out: output (B*S*D f32, 16 MB) ++ top_attn (B*S*S f32, 32 MB)
// d_ws (~2.13 MB): head-0 q/k (1 MB) + packed mask bits (1 MB) + stats (32 KB)
// Graph: 7 nodes (prep, gemm_qv, gemm_k, flash, cvt_Wo, gemm_o, prob_h0).
// ---------------------------------------------------------------------------
extern "C" void kernel_launch(void* const* d_in, const int* in_sizes, int n_in,
                              void* d_out, int out_size, void* d_ws, size_t ws_size,
                              hipStream_t stream) {
    const float* key_   = (const float*)d_in[0];
    const float* value_ = (const float*)d_in[1];
    const float* query_ = (const float*)d_in[2];
    const int*   mask_  = (const int*)d_in[3];
    const float* Wk = (const float*)d_in[4];
    const float* bk = (const float*)d_in[5];
    const float* Wv = (const float*)d_in[6];
    const float* bv = (const float*)d_in[7];
    const float* Wq = (const float*)d_in[8];
    const float* bq = (const float*)d_in[9];
    const float* Wo = (const float*)d_in[10];
    const float* bo = (const float*)d_in[11];

    constexpr size_t XS  = (size_t)BB * SS * DD;  // 4194304 elements
    constexpr size_t WSZ = (size_t)DD * DD;       // 1048576 elements

    float* out_f = (float*)d_out;
    unsigned short* scratch = (unsigned short*)(out_f + XS);
    unsigned short* qws = scratch;            // (B,H,S,DH)
    unsigned short* kws = qws + XS;           // (B,H,S,DH)
    unsigned short* vws = kws + XS;           // (B,H,DH,S)
    unsigned short* ctx = vws + XS;           // (B,S,D) — holds Wq/Wk/Wv bf16 pre-flash

    unsigned short* q0 = (unsigned short*)d_ws;             // [B][S][DH] head-0 q
    unsigned short* k0 = q0 + (size_t)BB * SS * DHH;        // [B][S][DH] head-0 k
    unsigned long long* pm = (unsigned long long*)(k0 + (size_t)BB * SS * DHH); // 1 MB
    float2* stats = (float2*)(pm + (size_t)BB * SS * (SS / 64));                // 32 KB

    // bf16 staging areas in dead regions
    unsigned short* Xq  = (unsigned short*)out_f;           // 8 MB (out region lo)
    unsigned short* Xk  = Xq + XS;                          // 8 MB (out region hi)
    unsigned short* Xv  = kws;                              // kws free till gemm-k
    unsigned short* Wqb = ctx;                              // ctx free till flash
    unsigned short* Wkb = Wqb + WSZ;
    unsigned short* Wvb = Wkb + WSZ;
    unsigned short* Wob = qws;                              // qws free after flash

    // q scale = 1/sqrt(DH) * log2(e)  -> exp2-based softmax downstream
    const float qscale = 0.125f * 1.4426950408889634f;

    // 1: all conversions + mask pack, one launch
    prep<<<15872, 256, 0, stream>>>(query_, key_, value_, Wq, Wk, Wv,
                                    Xq, Xk, Xv, Wqb, Wkb, Wvb, mask_, pm);

    // 2: fused Q + V projections (V must complete before K overwrites kws)
    gemm_qv<<<1024, 256, 0, stream>>>(Xq, Wqb, bq, qws, qscale, q0,
                                      Xv, Wvb, bv, vws);

    // 3: K projection (+ head-0 k export)
    gemm_one<0><<<512, 256, 0, stream>>>(Xk, Wkb, bk, kws, 1.0f, k0);

    // 4: flash attention (+ head-0 (M,L) stats)
    flash_attn<<<BB * HH * (SS / 128), 512, 0, stream>>>(qws, kws, vws, pm, ctx, stats);

    // 5: Wo -> bf16 (into qws region, dead after flash)
    cvt_bf16<<<WSZ / 2048, 256, 0, stream>>>(Wo, Wob);

    // 6: output projection
    gemm_one<2><<<512, 256, 0, stream>>>(ctx, Wob, bo, out_f, 1.0f, nullptr);

    // 7: head-0 probabilities in one pass over the scratch region
    prob_h0<<<512, 256, 0, stream>>>(q0, k0, pm, stats, out_f + XS);
}